// Round 2
// baseline (677.670 us; speedup 1.0000x reference)
//
#include <hip/hip_runtime.h>
#include <math.h>

#define NB 8192
#define ND 2048
#define NT 4

using bf16x8 = __attribute__((ext_vector_type(8))) short;
using f32x4  = __attribute__((ext_vector_type(4))) float;

__device__ inline unsigned short f2bf(float f) {
  unsigned int u = __float_as_uint(f);
  u += 0x7FFFu + ((u >> 16) & 1u);           // RNE
  return (unsigned short)(u >> 16);
}
__device__ inline void unpack8(uint4 u, float* f) {
  f[0] = __uint_as_float(u.x << 16); f[1] = __uint_as_float(u.x & 0xFFFF0000u);
  f[2] = __uint_as_float(u.y << 16); f[3] = __uint_as_float(u.y & 0xFFFF0000u);
  f[4] = __uint_as_float(u.z << 16); f[5] = __uint_as_float(u.z & 0xFFFF0000u);
  f[6] = __uint_as_float(u.w << 16); f[7] = __uint_as_float(u.w & 0xFFFF0000u);
}

#define GL2LDS(g, l) __builtin_amdgcn_global_load_lds( \
    (const __attribute__((address_space(1))) void*)(g), \
    (__attribute__((address_space(3))) void*)(l), 16, 0, 0)

// ---------- transpose+cast: WT[d][e] = (bf16)W[e][d], 2048x2048 ---------------
__global__ __launch_bounds__(256) void transpose_cast(
    const float* __restrict__ W, unsigned short* __restrict__ WT)
{
  __shared__ float tile[64][65];
  const int t = threadIdx.x, r = t >> 2, c0 = (t & 3) * 16;
  const int bx = blockIdx.x * 64, by = blockIdx.y * 64;
  const float* src = W + (size_t)(by + r) * ND + bx + c0;
#pragma unroll
  for (int j = 0; j < 4; ++j) {
    float4 v = *reinterpret_cast<const float4*>(src + j * 4);
    tile[r][c0 + j*4 + 0] = v.x; tile[r][c0 + j*4 + 1] = v.y;
    tile[r][c0 + j*4 + 2] = v.z; tile[r][c0 + j*4 + 3] = v.w;
  }
  __syncthreads();
  unsigned int pk[8];
#pragma unroll
  for (int j = 0; j < 8; ++j) {
    unsigned int lo = f2bf(tile[c0 + 2*j    ][r]);
    unsigned int hi = f2bf(tile[c0 + 2*j + 1][r]);
    pk[j] = lo | (hi << 16);
  }
  unsigned short* dst = WT + (size_t)(bx + r) * ND + by + c0;
  *reinterpret_cast<uint4*>(dst)     = make_uint4(pk[0], pk[1], pk[2], pk[3]);
  *reinterpret_cast<uint4*>(dst + 8) = make_uint4(pk[4], pk[5], pk[6], pk[7]);
}

// ---------- plain cast f32 -> bf16 (row-major copy) ---------------------------
__global__ __launch_bounds__(256) void cast_w(const float* __restrict__ w,
                                              unsigned short* __restrict__ o) {
  const size_t i4 = ((size_t)blockIdx.x * 256 + threadIdx.x) * 4;
  float4 f = *reinterpret_cast<const float4*>(w + i4);
  ushort4 r;
  r.x = f2bf(f.x); r.y = f2bf(f.y); r.z = f2bf(f.z); r.w = f2bf(f.w);
  *reinterpret_cast<ushort4*>(o + i4) = r;
}

// ---------- tokens + mask + LayerNorm -> F chunk (bf16) -----------------------
__global__ __launch_bounds__(256) void prep_tokens(
    const float* __restrict__ x_start, const int* __restrict__ tarr,
    const float* __restrict__ noise, const float* __restrict__ cond_src,
    const float* __restrict__ cond_tgt, const float* __restrict__ sqrt_ac,
    const float* __restrict__ sqrt_omac, unsigned short* __restrict__ F,
    float* __restrict__ maskf, int b0)
{
  const int cb = blockIdx.y, tok = blockIdx.x, tid = threadIdx.x;
  const int b = b0 + cb;
  const int e0 = tid * 8;
  float v[8];
  if (tok == 0) {
    const int tb = tarr[b];
    const float sa = sqrt_ac[tb], so = sqrt_omac[tb];
    const float4* xs = reinterpret_cast<const float4*>(x_start + (size_t)b * ND + e0);
    const float4* ns = reinterpret_cast<const float4*>(noise + (size_t)b * ND + e0);
    float4 x0 = xs[0], x1 = xs[1], n0 = ns[0], n1 = ns[1];
    v[0] = sa*x0.x + so*n0.x; v[1] = sa*x0.y + so*n0.y;
    v[2] = sa*x0.z + so*n0.z; v[3] = sa*x0.w + so*n0.w;
    v[4] = sa*x1.x + so*n1.x; v[5] = sa*x1.y + so*n1.y;
    v[6] = sa*x1.z + so*n1.z; v[7] = sa*x1.w + so*n1.w;
  } else if (tok == 1) {
    const float tf = (float)tarr[b];
    const float cc = -9.210340371976184f / 1023.0f;  // -ln(10000)/(half-1)
#pragma unroll
    for (int j = 0; j < 8; ++j) {
      int e = e0 + j;
      int i = (e < 1024) ? e : (e - 1024);
      float a = tf * expf((float)i * cc);
      v[j] = (e < 1024) ? sinf(a) : cosf(a);
    }
  } else {
    const float* src = (tok == 2) ? cond_src : cond_tgt;
    const float4* ps = reinterpret_cast<const float4*>(src + (size_t)b * ND + e0);
    float4 a0 = ps[0], a1 = ps[1];
    v[0]=a0.x; v[1]=a0.y; v[2]=a0.z; v[3]=a0.w;
    v[4]=a1.x; v[5]=a1.y; v[6]=a1.z; v[7]=a1.w;
  }
  float s = 0.f, s2 = 0.f, sab = 0.f;
#pragma unroll
  for (int j = 0; j < 8; ++j) { s += v[j]; s2 += v[j]*v[j]; sab += fabsf(v[j]); }
#pragma unroll
  for (int o = 32; o > 0; o >>= 1) {
    s += __shfl_xor(s, o); s2 += __shfl_xor(s2, o); sab += __shfl_xor(sab, o);
  }
  __shared__ float red[12];
  const int lane = tid & 63, wid = tid >> 6;
  if (lane == 0) { red[wid*3+0] = s; red[wid*3+1] = s2; red[wid*3+2] = sab; }
  __syncthreads();
  s   = red[0] + red[3] + red[6] + red[9];
  s2  = red[1] + red[4] + red[7] + red[10];
  sab = red[2] + red[5] + red[8] + red[11];
  const float mu  = s * (1.0f / ND);
  const float var = s2 * (1.0f / ND) - mu * mu;
  const float rs  = rsqrtf(var + 1e-5f);
  if (tid == 0) maskf[(size_t)cb*NT + tok] = (sab > 0.0f) ? 1.0f : 0.0f;
  unsigned int pk[4];
#pragma unroll
  for (int j = 0; j < 4; ++j) {
    unsigned int lo = f2bf((v[2*j]   - mu) * rs);
    unsigned int hi = f2bf((v[2*j+1] - mu) * rs);
    pk[j] = lo | (hi << 16);
  }
  *reinterpret_cast<uint4*>(F + ((size_t)cb*NT + tok) * ND + e0) =
      make_uint4(pk[0], pk[1], pk[2], pk[3]);
}

// ---------- GEMM core: C[m,n] = sum_k A[m,k]*B[n,k], K=N=2048, bf16 out -------
__global__ __launch_bounds__(256) void gemm_nt_bf16(
    const unsigned short* __restrict__ A, const unsigned short* __restrict__ B,
    unsigned short* __restrict__ C)
{
  constexpr int K = ND;
  __shared__ unsigned short As[128*32];
  __shared__ unsigned short Bs[128*32];
  const int tid = threadIdx.x;
  const int lane = tid & 63, wid = tid >> 6;
  const int wm = wid >> 1, wn = wid & 1;
  const size_t arow0 = (size_t)blockIdx.y * 128;
  const size_t bcol0 = (size_t)blockIdx.x * 128;
  f32x4 acc[4][4] = {};
  const int row0 = tid >> 2, kc = (tid & 3) * 8;
  const int row1 = row0 + 64;
  const unsigned short* ga0 = A + (arow0 + row0) * K + kc;
  const unsigned short* ga1 = A + (arow0 + row1) * K + kc;
  const unsigned short* gb0 = B + (bcol0 + row0) * K + kc;
  const unsigned short* gb1 = B + (bcol0 + row1) * K + kc;
  char* lAs = (char*)As; char* lBs = (char*)Bs;
  const int lo0 = wid * 1024, lo1 = 4096 + wid * 1024;
  const int ar = (lane & 15), ko = (lane >> 4) * 8;
  for (int k0 = 0; k0 < K; k0 += 32) {
    GL2LDS(ga0 + k0, lAs + lo0);
    GL2LDS(ga1 + k0, lAs + lo1);
    GL2LDS(gb0 + k0, lBs + lo0);
    GL2LDS(gb1 + k0, lBs + lo1);
    __syncthreads();
    bf16x8 af[4], bfr[4];
#pragma unroll
    for (int mi = 0; mi < 4; ++mi)
      af[mi] = *reinterpret_cast<const bf16x8*>(&As[(wm*64 + mi*16 + ar)*32 + ko]);
#pragma unroll
    for (int ni = 0; ni < 4; ++ni)
      bfr[ni] = *reinterpret_cast<const bf16x8*>(&Bs[(wn*64 + ni*16 + ar)*32 + ko]);
#pragma unroll
    for (int mi = 0; mi < 4; ++mi)
#pragma unroll
      for (int ni = 0; ni < 4; ++ni)
        acc[mi][ni] = __builtin_amdgcn_mfma_f32_16x16x32_bf16(af[mi], bfr[ni], acc[mi][ni], 0, 0, 0);
    __syncthreads();
  }
#pragma unroll
  for (int mi = 0; mi < 4; ++mi)
#pragma unroll
    for (int ni = 0; ni < 4; ++ni) {
      const size_t col = bcol0 + wn*64 + ni*16 + (lane & 15);
#pragma unroll
      for (int r = 0; r < 4; ++r) {
        const size_t row = arow0 + wm*64 + mi*16 + (lane >> 4)*4 + r;
        C[row * ND + col] = f2bf(acc[mi][ni][r]);
      }
    }
}

// ---------- pred GEMM: f32 out to d_out(+1) + loss partials -------------------
__global__ __launch_bounds__(256) void gemm_nt_pred(
    const unsigned short* __restrict__ A, const unsigned short* __restrict__ B,
    float* __restrict__ outp /* = out+1 */, const float* __restrict__ x_start,
    float* __restrict__ lpart, int b0)
{
  constexpr int K = ND;
  __shared__ unsigned short As[128*32];
  __shared__ unsigned short Bs[128*32];
  __shared__ float r2[4];
  const int tid = threadIdx.x;
  const int lane = tid & 63, wid = tid >> 6;
  const int wm = wid >> 1, wn = wid & 1;
  const size_t arow0 = (size_t)blockIdx.y * 128;
  const size_t bcol0 = (size_t)blockIdx.x * 128;
  f32x4 acc[4][4] = {};
  const int row0 = tid >> 2, kc = (tid & 3) * 8;
  const int row1 = row0 + 64;
  const unsigned short* ga0 = A + (arow0 + row0) * K + kc;
  const unsigned short* ga1 = A + (arow0 + row1) * K + kc;
  const unsigned short* gb0 = B + (bcol0 + row0) * K + kc;
  const unsigned short* gb1 = B + (bcol0 + row1) * K + kc;
  char* lAs = (char*)As; char* lBs = (char*)Bs;
  const int lo0 = wid * 1024, lo1 = 4096 + wid * 1024;
  const int ar = (lane & 15), ko = (lane >> 4) * 8;
  for (int k0 = 0; k0 < K; k0 += 32) {
    GL2LDS(ga0 + k0, lAs + lo0);
    GL2LDS(ga1 + k0, lAs + lo1);
    GL2LDS(gb0 + k0, lBs + lo0);
    GL2LDS(gb1 + k0, lBs + lo1);
    __syncthreads();
    bf16x8 af[4], bfr[4];
#pragma unroll
    for (int mi = 0; mi < 4; ++mi)
      af[mi] = *reinterpret_cast<const bf16x8*>(&As[(wm*64 + mi*16 + ar)*32 + ko]);
#pragma unroll
    for (int ni = 0; ni < 4; ++ni)
      bfr[ni] = *reinterpret_cast<const bf16x8*>(&Bs[(wn*64 + ni*16 + ar)*32 + ko]);
#pragma unroll
    for (int mi = 0; mi < 4; ++mi)
#pragma unroll
      for (int ni = 0; ni < 4; ++ni)
        acc[mi][ni] = __builtin_amdgcn_mfma_f32_16x16x32_bf16(af[mi], bfr[ni], acc[mi][ni], 0, 0, 0);
    __syncthreads();
  }
  float sse = 0.f;
#pragma unroll
  for (int mi = 0; mi < 4; ++mi)
#pragma unroll
    for (int ni = 0; ni < 4; ++ni) {
      const size_t col = bcol0 + wn*64 + ni*16 + (lane & 15);
#pragma unroll
      for (int r = 0; r < 4; ++r) {
        const size_t row = arow0 + wm*64 + mi*16 + (lane >> 4)*4 + r;  // chunk-local b
        const size_t gb  = (size_t)b0 + row;                           // global b
        const float p = acc[mi][ni][r];
        outp[gb * ND + col] = p;
        const float d = p - x_start[gb * ND + col];
        sse += d * d;
      }
    }
#pragma unroll
  for (int o = 32; o > 0; o >>= 1) sse += __shfl_xor(sse, o);
  if (lane == 0) r2[wid] = sse;
  __syncthreads();
  if (tid == 0) {
    const int slot = ((b0 >> 7) + (int)blockIdx.y) * 16 + (int)blockIdx.x;
    lpart[slot] = r2[0] + r2[1] + r2[2] + r2[3];
  }
}

// ---------- per-group: logits from F,H -> softmax -> u = sum_j c_j f_j --------
__global__ __launch_bounds__(256) void attn_u(
    const unsigned short* __restrict__ F, const unsigned short* __restrict__ H,
    const float* __restrict__ maskf, unsigned short* __restrict__ U)
{
  const int cb = blockIdx.x, tid = threadIdx.x;
  const int e0 = tid * 8, lane = tid & 63, wid = tid >> 6;
  __shared__ float red[64];
  float f[4][8], h[4][8];
#pragma unroll
  for (int i = 0; i < 4; ++i) {
    unpack8(*reinterpret_cast<const uint4*>(F + ((size_t)cb*4 + i)*ND + e0), f[i]);
    unpack8(*reinterpret_cast<const uint4*>(H + ((size_t)cb*4 + i)*ND + e0), h[i]);
  }
  float part[16];
#pragma unroll
  for (int i = 0; i < 4; ++i)
#pragma unroll
    for (int j = 0; j < 4; ++j) {
      float p = 0.f;
#pragma unroll
      for (int r = 0; r < 8; ++r) p += f[i][r] * h[j][r];
      part[i*4+j] = p;
    }
#pragma unroll
  for (int idx = 0; idx < 16; ++idx)
#pragma unroll
    for (int o = 32; o > 0; o >>= 1) part[idx] += __shfl_xor(part[idx], o);
  if (lane == 0) {
#pragma unroll
    for (int idx = 0; idx < 16; ++idx) red[wid*16 + idx] = part[idx];
  }
  __syncthreads();
  float lg[16];
#pragma unroll
  for (int idx = 0; idx < 16; ++idx)
    lg[idx] = red[idx] + red[16+idx] + red[32+idx] + red[48+idx];

  const float scale = 0.022097086912079608f;  // 2048^-0.5
  float m[4];
#pragma unroll
  for (int j = 0; j < 4; ++j) m[j] = maskf[(size_t)cb*NT + j];
  const float denom = fmaxf(m[0]+m[1]+m[2]+m[3], 1.0f);
  float c[4] = {0.f, 0.f, 0.f, 0.f};
#pragma unroll
  for (int i = 0; i < 4; ++i) {
    float x[4];
#pragma unroll
    for (int j = 0; j < 4; ++j) x[j] = (m[j] > 0.f) ? lg[i*4+j]*scale : -1e9f;
    const float mx = fmaxf(fmaxf(x[0],x[1]), fmaxf(x[2],x[3]));
    float p[4], sum = 0.f;
#pragma unroll
    for (int j = 0; j < 4; ++j) { p[j] = expf(x[j]-mx); sum += p[j]; }
    const float w = m[i] / (sum * denom);
#pragma unroll
    for (int j = 0; j < 4; ++j) c[j] += p[j] * w;
  }
  unsigned int pk[4];
#pragma unroll
  for (int jj = 0; jj < 4; ++jj) {
    float ulo = c[0]*f[0][2*jj]   + c[1]*f[1][2*jj]   + c[2]*f[2][2*jj]   + c[3]*f[3][2*jj];
    float uhi = c[0]*f[0][2*jj+1] + c[1]*f[1][2*jj+1] + c[2]*f[2][2*jj+1] + c[3]*f[3][2*jj+1];
    pk[jj] = (unsigned int)f2bf(ulo) | ((unsigned int)f2bf(uhi) << 16);
  }
  *reinterpret_cast<uint4*>(U + (size_t)cb*ND + e0) = make_uint4(pk[0],pk[1],pk[2],pk[3]);
}

// ---------- deterministic loss reduce (1024 fixed slots) ----------------------
__global__ __launch_bounds__(256) void loss_final(const float* __restrict__ lpart,
                                                  float* __restrict__ out) {
  const int tid = threadIdx.x;
  float s = 0.f;
  for (int i = tid; i < 1024; i += 256) s += lpart[i];
#pragma unroll
  for (int o = 32; o > 0; o >>= 1) s += __shfl_xor(s, o);
  __shared__ float red[4];
  const int lane = tid & 63, wid = tid >> 6;
  if (lane == 0) red[wid] = s;
  __syncthreads();
  if (tid == 0) out[0] = (red[0]+red[1]+red[2]+red[3]) * (1.0f / 16777216.0f);
}

extern "C" void kernel_launch(void* const* d_in, const int* in_sizes, int n_in,
                              void* d_out, int out_size, void* d_ws, size_t ws_size,
                              hipStream_t stream) {
  const float* x_start   = (const float*)d_in[0];
  const int*   tarr      = (const int*)  d_in[1];
  const float* noise     = (const float*)d_in[2];
  const float* cond_src  = (const float*)d_in[3];
  const float* cond_tgt  = (const float*)d_in[4];
  const float* w_q       = (const float*)d_in[5];
  const float* w_k       = (const float*)d_in[6];
  const float* w_v       = (const float*)d_in[7];
  const float* sqrt_ac   = (const float*)d_in[8];
  const float* sqrt_omac = (const float*)d_in[9];
  float* out = (float*)d_out;
  char*  ws  = (char*)d_ws;

  // adaptive chunk size: need(cb) = 16 MiB (G+Wv) + cb*36880 (F+H+U+mask) + 4 KiB
  size_t CB;
  if      (ws_size >= 318902272ull) CB = 8192;
  else if (ws_size >= 167841792ull) CB = 4096;
  else if (ws_size >=  92311552ull) CB = 2048;
  else if (ws_size >=  54546432ull) CB = 1024;
  else return;  // < 52 MiB workspace: cannot run

  const size_t offG  = 0;
  const size_t offWv = 8388608;
  const size_t offF  = 16777216;
  const size_t szF   = CB * 16384;            // 4*CB*2048*2 bytes
  const size_t offH  = offF + szF;
  const size_t offU  = offH + szF;
  const size_t offMask = offU + CB * 4096;
  const size_t offLp   = offMask + CB * 16;

  unsigned short* G    = (unsigned short*)(ws + offG);
  unsigned short* WvBf = (unsigned short*)(ws + offWv);
  unsigned short* F    = (unsigned short*)(ws + offF);
  unsigned short* H    = (unsigned short*)(ws + offH);
  unsigned short* U    = (unsigned short*)(ws + offU);
  float* maskC = (float*)(ws + offMask);
  float* lpart = (float*)(ws + offLp);
  // setup-phase aliases (dead before chunk 0 writes F/H)
  unsigned short* WqT = F;
  unsigned short* WkT = H;

  transpose_cast<<<dim3(32, 32), 256, 0, stream>>>(w_q, WqT);
  transpose_cast<<<dim3(32, 32), 256, 0, stream>>>(w_k, WkT);
  cast_w<<<dim3(4096), 256, 0, stream>>>(w_v, WvBf);
  gemm_nt_bf16<<<dim3(16, 16), 256, 0, stream>>>(WqT, WkT, G);   // G = Wq^T Wk

  const int nchunks = NB / (int)CB;
  for (int ci = 0; ci < nchunks; ++ci) {
    const int b0 = ci * (int)CB;
    prep_tokens<<<dim3(NT, (int)CB), 256, 0, stream>>>(
        x_start, tarr, noise, cond_src, cond_tgt, sqrt_ac, sqrt_omac, F, maskC, b0);
    gemm_nt_bf16<<<dim3(16, (int)CB / 32), 256, 0, stream>>>(F, G, H);  // H = F G^T
    attn_u<<<dim3((int)CB), 256, 0, stream>>>(F, H, maskC, U);
    gemm_nt_pred<<<dim3(16, (int)CB / 128), 256, 0, stream>>>(
        U, WvBf, out + 1, x_start, lpart, b0);                          // pred = U Wv^T
  }
  loss_final<<<dim3(1), 256, 0, stream>>>(lpart, out);
}

// Round 3
// 628.641 us; speedup vs baseline: 1.0780x; 1.0780x over previous
//
#include <hip/hip_runtime.h>
#include <math.h>

#define NB 8192
#define ND 2048
#define NT 4

using bf16x8 = __attribute__((ext_vector_type(8))) short;
using f32x4  = __attribute__((ext_vector_type(4))) float;

__device__ inline unsigned short f2bf(float f) {
  unsigned int u = __float_as_uint(f);
  u += 0x7FFFu + ((u >> 16) & 1u);           // RNE
  return (unsigned short)(u >> 16);
}
__device__ inline void unpack8(uint4 u, float* f) {
  f[0] = __uint_as_float(u.x << 16); f[1] = __uint_as_float(u.x & 0xFFFF0000u);
  f[2] = __uint_as_float(u.y << 16); f[3] = __uint_as_float(u.y & 0xFFFF0000u);
  f[4] = __uint_as_float(u.z << 16); f[5] = __uint_as_float(u.z & 0xFFFF0000u);
  f[6] = __uint_as_float(u.w << 16); f[7] = __uint_as_float(u.w & 0xFFFF0000u);
}

#define GL2LDS(g, l) __builtin_amdgcn_global_load_lds( \
    (const __attribute__((address_space(1))) void*)(g), \
    (__attribute__((address_space(3))) void*)(l), 16, 0, 0)

__device__ inline void waitv8() { asm volatile("s_waitcnt vmcnt(8)" ::: "memory"); }
__device__ inline void waitv4() { asm volatile("s_waitcnt vmcnt(4)" ::: "memory"); }
__device__ inline void waitv0() { asm volatile("s_waitcnt vmcnt(0)" ::: "memory"); }

// ---------- transpose+cast: WT[d][e] = (bf16)W[e][d], 2048x2048 ---------------
__global__ __launch_bounds__(256) void transpose_cast(
    const float* __restrict__ W, unsigned short* __restrict__ WT)
{
  __shared__ float tile[64][65];
  const int t = threadIdx.x, r = t >> 2, c0 = (t & 3) * 16;
  const int bx = blockIdx.x * 64, by = blockIdx.y * 64;
  const float* src = W + (size_t)(by + r) * ND + bx + c0;
#pragma unroll
  for (int j = 0; j < 4; ++j) {
    float4 v = *reinterpret_cast<const float4*>(src + j * 4);
    tile[r][c0 + j*4 + 0] = v.x; tile[r][c0 + j*4 + 1] = v.y;
    tile[r][c0 + j*4 + 2] = v.z; tile[r][c0 + j*4 + 3] = v.w;
  }
  __syncthreads();
  unsigned int pk[8];
#pragma unroll
  for (int j = 0; j < 8; ++j) {
    unsigned int lo = f2bf(tile[c0 + 2*j    ][r]);
    unsigned int hi = f2bf(tile[c0 + 2*j + 1][r]);
    pk[j] = lo | (hi << 16);
  }
  unsigned short* dst = WT + (size_t)(bx + r) * ND + by + c0;
  *reinterpret_cast<uint4*>(dst)     = make_uint4(pk[0], pk[1], pk[2], pk[3]);
  *reinterpret_cast<uint4*>(dst + 8) = make_uint4(pk[4], pk[5], pk[6], pk[7]);
}

// ---------- plain cast f32 -> bf16 (row-major copy) ---------------------------
__global__ __launch_bounds__(256) void cast_w(const float* __restrict__ w,
                                              unsigned short* __restrict__ o) {
  const size_t i4 = ((size_t)blockIdx.x * 256 + threadIdx.x) * 4;
  float4 f = *reinterpret_cast<const float4*>(w + i4);
  ushort4 r;
  r.x = f2bf(f.x); r.y = f2bf(f.y); r.z = f2bf(f.z); r.w = f2bf(f.w);
  *reinterpret_cast<ushort4*>(o + i4) = r;
}

// ---------- tokens + mask + LayerNorm -> F chunk (bf16) -----------------------
__global__ __launch_bounds__(256) void prep_tokens(
    const float* __restrict__ x_start, const int* __restrict__ tarr,
    const float* __restrict__ noise, const float* __restrict__ cond_src,
    const float* __restrict__ cond_tgt, const float* __restrict__ sqrt_ac,
    const float* __restrict__ sqrt_omac, unsigned short* __restrict__ F,
    float* __restrict__ maskf, int b0)
{
  const int cb = blockIdx.y, tok = blockIdx.x, tid = threadIdx.x;
  const int b = b0 + cb;
  const int e0 = tid * 8;
  float v[8];
  if (tok == 0) {
    const int tb = tarr[b];
    const float sa = sqrt_ac[tb], so = sqrt_omac[tb];
    const float4* xs = reinterpret_cast<const float4*>(x_start + (size_t)b * ND + e0);
    const float4* ns = reinterpret_cast<const float4*>(noise + (size_t)b * ND + e0);
    float4 x0 = xs[0], x1 = xs[1], n0 = ns[0], n1 = ns[1];
    v[0] = sa*x0.x + so*n0.x; v[1] = sa*x0.y + so*n0.y;
    v[2] = sa*x0.z + so*n0.z; v[3] = sa*x0.w + so*n0.w;
    v[4] = sa*x1.x + so*n1.x; v[5] = sa*x1.y + so*n1.y;
    v[6] = sa*x1.z + so*n1.z; v[7] = sa*x1.w + so*n1.w;
  } else if (tok == 1) {
    const float tf = (float)tarr[b];
    const float cc = -9.210340371976184f / 1023.0f;  // -ln(10000)/(half-1)
#pragma unroll
    for (int j = 0; j < 8; ++j) {
      int e = e0 + j;
      int i = (e < 1024) ? e : (e - 1024);
      float a = tf * expf((float)i * cc);
      v[j] = (e < 1024) ? sinf(a) : cosf(a);
    }
  } else {
    const float* src = (tok == 2) ? cond_src : cond_tgt;
    const float4* ps = reinterpret_cast<const float4*>(src + (size_t)b * ND + e0);
    float4 a0 = ps[0], a1 = ps[1];
    v[0]=a0.x; v[1]=a0.y; v[2]=a0.z; v[3]=a0.w;
    v[4]=a1.x; v[5]=a1.y; v[6]=a1.z; v[7]=a1.w;
  }
  float s = 0.f, s2 = 0.f, sab = 0.f;
#pragma unroll
  for (int j = 0; j < 8; ++j) { s += v[j]; s2 += v[j]*v[j]; sab += fabsf(v[j]); }
#pragma unroll
  for (int o = 32; o > 0; o >>= 1) {
    s += __shfl_xor(s, o); s2 += __shfl_xor(s2, o); sab += __shfl_xor(sab, o);
  }
  __shared__ float red[12];
  const int lane = tid & 63, wid = tid >> 6;
  if (lane == 0) { red[wid*3+0] = s; red[wid*3+1] = s2; red[wid*3+2] = sab; }
  __syncthreads();
  s   = red[0] + red[3] + red[6] + red[9];
  s2  = red[1] + red[4] + red[7] + red[10];
  sab = red[2] + red[5] + red[8] + red[11];
  const float mu  = s * (1.0f / ND);
  const float var = s2 * (1.0f / ND) - mu * mu;
  const float rs  = rsqrtf(var + 1e-5f);
  if (tid == 0) maskf[(size_t)cb*NT + tok] = (sab > 0.0f) ? 1.0f : 0.0f;
  unsigned int pk[4];
#pragma unroll
  for (int j = 0; j < 4; ++j) {
    unsigned int lo = f2bf((v[2*j]   - mu) * rs);
    unsigned int hi = f2bf((v[2*j+1] - mu) * rs);
    pk[j] = lo | (hi << 16);
  }
  *reinterpret_cast<uint4*>(F + ((size_t)cb*NT + tok) * ND + e0) =
      make_uint4(pk[0], pk[1], pk[2], pk[3]);
}

// ---------- old 128^2 GEMM core: C[m,n]=sum_k A[m,k]*B[n,k], bf16 out ---------
__global__ __launch_bounds__(256) void gemm_nt_bf16(
    const unsigned short* __restrict__ A, const unsigned short* __restrict__ B,
    unsigned short* __restrict__ C)
{
  constexpr int K = ND;
  __shared__ unsigned short As[128*32];
  __shared__ unsigned short Bs[128*32];
  const int tid = threadIdx.x;
  const int lane = tid & 63, wid = tid >> 6;
  const int wm = wid >> 1, wn = wid & 1;
  const size_t arow0 = (size_t)blockIdx.y * 128;
  const size_t bcol0 = (size_t)blockIdx.x * 128;
  f32x4 acc[4][4] = {};
  const int row0 = tid >> 2, kc = (tid & 3) * 8;
  const int row1 = row0 + 64;
  const unsigned short* ga0 = A + (arow0 + row0) * K + kc;
  const unsigned short* ga1 = A + (arow0 + row1) * K + kc;
  const unsigned short* gb0 = B + (bcol0 + row0) * K + kc;
  const unsigned short* gb1 = B + (bcol0 + row1) * K + kc;
  char* lAs = (char*)As; char* lBs = (char*)Bs;
  const int lo0 = wid * 1024, lo1 = 4096 + wid * 1024;
  const int ar = (lane & 15), ko = (lane >> 4) * 8;
  for (int k0 = 0; k0 < K; k0 += 32) {
    GL2LDS(ga0 + k0, lAs + lo0);
    GL2LDS(ga1 + k0, lAs + lo1);
    GL2LDS(gb0 + k0, lBs + lo0);
    GL2LDS(gb1 + k0, lBs + lo1);
    __syncthreads();
    bf16x8 af[4], bfr[4];
#pragma unroll
    for (int mi = 0; mi < 4; ++mi)
      af[mi] = *reinterpret_cast<const bf16x8*>(&As[(wm*64 + mi*16 + ar)*32 + ko]);
#pragma unroll
    for (int ni = 0; ni < 4; ++ni)
      bfr[ni] = *reinterpret_cast<const bf16x8*>(&Bs[(wn*64 + ni*16 + ar)*32 + ko]);
#pragma unroll
    for (int mi = 0; mi < 4; ++mi)
#pragma unroll
      for (int ni = 0; ni < 4; ++ni)
        acc[mi][ni] = __builtin_amdgcn_mfma_f32_16x16x32_bf16(af[mi], bfr[ni], acc[mi][ni], 0, 0, 0);
    __syncthreads();
  }
#pragma unroll
  for (int mi = 0; mi < 4; ++mi)
#pragma unroll
    for (int ni = 0; ni < 4; ++ni) {
      const size_t col = bcol0 + wn*64 + ni*16 + (lane & 15);
#pragma unroll
      for (int r = 0; r < 4; ++r) {
        const size_t row = arow0 + wm*64 + mi*16 + (lane >> 4)*4 + r;
        C[row * ND + col] = f2bf(acc[mi][ni][r]);
      }
    }
}

// ---------- NEW 256^2 tile, BK=32, ring-4 LDS, counted-vmcnt pipeline ---------
// C[m,n] = sum_k A[m,k]*B[n,k]; K = N(B rows stride) = 2048; C row-major ld 2048
// 512 threads = 8 waves (2 M x 4 N). Per-wave C: 128x64 = acc[8][4].
// LDS bijection: slot s<->(r=s>>2, c=(s&3)^(r&3)); staged via pre-swizzled
// global source (linear LDS dest), read back conflict-free (2 lanes/bank).
__global__ __launch_bounds__(512, 2) void gemm_nt_256(
    const unsigned short* __restrict__ A, const unsigned short* __restrict__ B,
    unsigned short* __restrict__ C)
{
  constexpr int K = 2048;
  constexpr int NTILE = K / 32;  // 64
  __shared__ unsigned short lds[65536];  // 128 KiB: 4 rings x (A 16K + B 16K)
  const int tid = threadIdx.x;
  const int lane = tid & 63, wid = tid >> 6;
  const int wm = wid >> 2, wn = wid & 3;
  const size_t arow0 = (size_t)blockIdx.y * 256;
  const size_t bcol0 = (size_t)blockIdx.x * 256;
  char* ldsb = (char*)lds;

  // ---- staging addresses (2 A-loads + 2 B-loads per thread per tile) ----
  const int s0 = wid*64 + lane, s1 = s0 + 512;
  const int rS0 = s0 >> 2, cS0 = (s0 & 3) ^ (rS0 & 3);
  const int rS1 = s1 >> 2, cS1 = (s1 & 3) ^ (rS1 & 3);
  const unsigned short* gA0 = A + (arow0 + rS0) * K + cS0*8;
  const unsigned short* gA1 = A + (arow0 + rS1) * K + cS1*8;
  const unsigned short* gB0 = B + (bcol0 + rS0) * K + cS0*8;
  const unsigned short* gB1 = B + (bcol0 + rS1) * K + cS1*8;
  const int ldsw0 = wid * 1024;          // round-0 uniform base (bytes)
  const int ldsw1 = 8192 + wid * 1024;   // round-1

#define STAGE_A(tt) { const int q_ = (tt)&3, k_ = (tt)*32;                 \
    GL2LDS(gA0 + k_, ldsb + q_*32768 + ldsw0);                             \
    GL2LDS(gA1 + k_, ldsb + q_*32768 + ldsw1); }
#define STAGE_B(tt) { const int q_ = (tt)&3, k_ = (tt)*32;                 \
    GL2LDS(gB0 + k_, ldsb + q_*32768 + 16384 + ldsw0);                     \
    GL2LDS(gB1 + k_, ldsb + q_*32768 + 16384 + ldsw1); }

  // ---- fragment read offset (bytes, within A or B region of a ring) ----
  const int lo16 = ((lane & 15) * 4 + ((lane >> 4) ^ (lane & 3))) * 16;

  f32x4 acc[8][4] = {};
  bf16x8 af[4], bfr[4];

  // prologue: stage tiles 0,1,2; wait tile 0 (8 loads of tiles 1,2 in flight)
  STAGE_A(0); STAGE_B(0);
  STAGE_A(1); STAGE_B(1);
  STAGE_A(2); STAGE_B(2);
  waitv8();
  __builtin_amdgcn_s_barrier();

  for (int t = 0; t < NTILE; ++t) {
    const char* bA = ldsb + (t & 3) * 32768;
    const char* bB = bA + 16384;
    // ---- phase 0: read A-half0 + all B frags; stage A of t+3 ----
#pragma unroll
    for (int mi = 0; mi < 4; ++mi)
      af[mi] = *reinterpret_cast<const bf16x8*>(bA + wm*8192 + mi*1024 + lo16);
#pragma unroll
    for (int ni = 0; ni < 4; ++ni)
      bfr[ni] = *reinterpret_cast<const bf16x8*>(bB + wn*4096 + ni*1024 + lo16);
    if (t < NTILE - 3) STAGE_A(t + 3);
    __builtin_amdgcn_s_barrier();
    __builtin_amdgcn_s_setprio(1);
#pragma unroll
    for (int mi = 0; mi < 4; ++mi)
#pragma unroll
      for (int ni = 0; ni < 4; ++ni)
        acc[mi][ni] = __builtin_amdgcn_mfma_f32_16x16x32_bf16(af[mi], bfr[ni], acc[mi][ni], 0, 0, 0);
    __builtin_amdgcn_s_setprio(0);
    __builtin_amdgcn_s_barrier();
    // ---- phase 1: read A-half1 (B frags still live); stage B of t+3 ----
#pragma unroll
    for (int mi = 0; mi < 4; ++mi)
      af[mi] = *reinterpret_cast<const bf16x8*>(bA + wm*8192 + (mi+4)*1024 + lo16);
    if (t < NTILE - 3) STAGE_B(t + 3);
    __builtin_amdgcn_s_barrier();
    __builtin_amdgcn_s_setprio(1);
#pragma unroll
    for (int mi = 0; mi < 4; ++mi)
#pragma unroll
      for (int ni = 0; ni < 4; ++ni)
        acc[mi+4][ni] = __builtin_amdgcn_mfma_f32_16x16x32_bf16(af[mi], bfr[ni], acc[mi+4][ni], 0, 0, 0);
    __builtin_amdgcn_s_setprio(0);
    // ---- boundary: counted wait -> tile t+1 resident; then barrier ----
    if (t < NTILE - 3)       waitv8();
    else if (t == NTILE - 3) waitv4();
    else if (t == NTILE - 2) waitv0();
    __builtin_amdgcn_s_barrier();
  }
#undef STAGE_A
#undef STAGE_B

  // epilogue: C/D layout col=lane&15, row=(lane>>4)*4+reg
#pragma unroll
  for (int mi = 0; mi < 8; ++mi)
#pragma unroll
    for (int ni = 0; ni < 4; ++ni) {
      const size_t col = bcol0 + wn*64 + ni*16 + (lane & 15);
#pragma unroll
      for (int r = 0; r < 4; ++r) {
        const size_t row = arow0 + wm*128 + mi*16 + (lane >> 4)*4 + r;
        C[row * 2048 + col] = f2bf(acc[mi][ni][r]);
      }
    }
}

// ---------- pred GEMM: f32 out to d_out(+1) + loss partials -------------------
__global__ __launch_bounds__(256) void gemm_nt_pred(
    const unsigned short* __restrict__ A, const unsigned short* __restrict__ B,
    float* __restrict__ outp /* = out+1 */, const float* __restrict__ x_start,
    float* __restrict__ lpart, int b0)
{
  constexpr int K = ND;
  __shared__ unsigned short As[128*32];
  __shared__ unsigned short Bs[128*32];
  __shared__ float r2[4];
  const int tid = threadIdx.x;
  const int lane = tid & 63, wid = tid >> 6;
  const int wm = wid >> 1, wn = wid & 1;
  const size_t arow0 = (size_t)blockIdx.y * 128;
  const size_t bcol0 = (size_t)blockIdx.x * 128;
  f32x4 acc[4][4] = {};
  const int row0 = tid >> 2, kc = (tid & 3) * 8;
  const int row1 = row0 + 64;
  const unsigned short* ga0 = A + (arow0 + row0) * K + kc;
  const unsigned short* ga1 = A + (arow0 + row1) * K + kc;
  const unsigned short* gb0 = B + (bcol0 + row0) * K + kc;
  const unsigned short* gb1 = B + (bcol0 + row1) * K + kc;
  char* lAs = (char*)As; char* lBs = (char*)Bs;
  const int lo0 = wid * 1024, lo1 = 4096 + wid * 1024;
  const int ar = (lane & 15), ko = (lane >> 4) * 8;
  for (int k0 = 0; k0 < K; k0 += 32) {
    GL2LDS(ga0 + k0, lAs + lo0);
    GL2LDS(ga1 + k0, lAs + lo1);
    GL2LDS(gb0 + k0, lBs + lo0);
    GL2LDS(gb1 + k0, lBs + lo1);
    __syncthreads();
    bf16x8 af[4], bfr[4];
#pragma unroll
    for (int mi = 0; mi < 4; ++mi)
      af[mi] = *reinterpret_cast<const bf16x8*>(&As[(wm*64 + mi*16 + ar)*32 + ko]);
#pragma unroll
    for (int ni = 0; ni < 4; ++ni)
      bfr[ni] = *reinterpret_cast<const bf16x8*>(&Bs[(wn*64 + ni*16 + ar)*32 + ko]);
#pragma unroll
    for (int mi = 0; mi < 4; ++mi)
#pragma unroll
      for (int ni = 0; ni < 4; ++ni)
        acc[mi][ni] = __builtin_amdgcn_mfma_f32_16x16x32_bf16(af[mi], bfr[ni], acc[mi][ni], 0, 0, 0);
    __syncthreads();
  }
  float sse = 0.f;
#pragma unroll
  for (int mi = 0; mi < 4; ++mi)
#pragma unroll
    for (int ni = 0; ni < 4; ++ni) {
      const size_t col = bcol0 + wn*64 + ni*16 + (lane & 15);
#pragma unroll
      for (int r = 0; r < 4; ++r) {
        const size_t row = arow0 + wm*64 + mi*16 + (lane >> 4)*4 + r;  // chunk-local b
        const size_t gb  = (size_t)b0 + row;                           // global b
        const float p = acc[mi][ni][r];
        outp[gb * ND + col] = p;
        const float d = p - x_start[gb * ND + col];
        sse += d * d;
      }
    }
#pragma unroll
  for (int o = 32; o > 0; o >>= 1) sse += __shfl_xor(sse, o);
  if (lane == 0) r2[wid] = sse;
  __syncthreads();
  if (tid == 0) {
    const int slot = ((b0 >> 7) + (int)blockIdx.y) * 16 + (int)blockIdx.x;
    lpart[slot] = r2[0] + r2[1] + r2[2] + r2[3];
  }
}

// ---------- per-group: logits from F,H -> softmax -> u = sum_j c_j f_j --------
__global__ __launch_bounds__(256) void attn_u(
    const unsigned short* __restrict__ F, const unsigned short* __restrict__ H,
    const float* __restrict__ maskf, unsigned short* __restrict__ U)
{
  const int cb = blockIdx.x, tid = threadIdx.x;
  const int e0 = tid * 8, lane = tid & 63, wid = tid >> 6;
  __shared__ float red[64];
  float f[4][8], h[4][8];
#pragma unroll
  for (int i = 0; i < 4; ++i) {
    unpack8(*reinterpret_cast<const uint4*>(F + ((size_t)cb*4 + i)*ND + e0), f[i]);
    unpack8(*reinterpret_cast<const uint4*>(H + ((size_t)cb*4 + i)*ND + e0), h[i]);
  }
  float part[16];
#pragma unroll
  for (int i = 0; i < 4; ++i)
#pragma unroll
    for (int j = 0; j < 4; ++j) {
      float p = 0.f;
#pragma unroll
      for (int r = 0; r < 8; ++r) p += f[i][r] * h[j][r];
      part[i*4+j] = p;
    }
#pragma unroll
  for (int idx = 0; idx < 16; ++idx)
#pragma unroll
    for (int o = 32; o > 0; o >>= 1) part[idx] += __shfl_xor(part[idx], o);
  if (lane == 0) {
#pragma unroll
    for (int idx = 0; idx < 16; ++idx) red[wid*16 + idx] = part[idx];
  }
  __syncthreads();
  float lg[16];
#pragma unroll
  for (int idx = 0; idx < 16; ++idx)
    lg[idx] = red[idx] + red[16+idx] + red[32+idx] + red[48+idx];

  const float scale = 0.022097086912079608f;  // 2048^-0.5
  float m[4];
#pragma unroll
  for (int j = 0; j < 4; ++j) m[j] = maskf[(size_t)cb*NT + j];
  const float denom = fmaxf(m[0]+m[1]+m[2]+m[3], 1.0f);
  float c[4] = {0.f, 0.f, 0.f, 0.f};
#pragma unroll
  for (int i = 0; i < 4; ++i) {
    float x[4];
#pragma unroll
    for (int j = 0; j < 4; ++j) x[j] = (m[j] > 0.f) ? lg[i*4+j]*scale : -1e9f;
    const float mx = fmaxf(fmaxf(x[0],x[1]), fmaxf(x[2],x[3]));
    float p[4], sum = 0.f;
#pragma unroll
    for (int j = 0; j < 4; ++j) { p[j] = expf(x[j]-mx); sum += p[j]; }
    const float w = m[i] / (sum * denom);
#pragma unroll
    for (int j = 0; j < 4; ++j) c[j] += p[j] * w;
  }
  unsigned int pk[4];
#pragma unroll
  for (int jj = 0; jj < 4; ++jj) {
    float ulo = c[0]*f[0][2*jj]   + c[1]*f[1][2*jj]   + c[2]*f[2][2*jj]   + c[3]*f[3][2*jj];
    float uhi = c[0]*f[0][2*jj+1] + c[1]*f[1][2*jj+1] + c[2]*f[2][2*jj+1] + c[3]*f[3][2*jj+1];
    pk[jj] = (unsigned int)f2bf(ulo) | ((unsigned int)f2bf(uhi) << 16);
  }
  *reinterpret_cast<uint4*>(U + (size_t)cb*ND + e0) = make_uint4(pk[0],pk[1],pk[2],pk[3]);
}

// ---------- deterministic loss reduce (1024 fixed slots) ----------------------
__global__ __launch_bounds__(256) void loss_final(const float* __restrict__ lpart,
                                                  float* __restrict__ out) {
  const int tid = threadIdx.x;
  float s = 0.f;
  for (int i = tid; i < 1024; i += 256) s += lpart[i];
#pragma unroll
  for (int o = 32; o > 0; o >>= 1) s += __shfl_xor(s, o);
  __shared__ float red[4];
  const int lane = tid & 63, wid = tid >> 6;
  if (lane == 0) red[wid] = s;
  __syncthreads();
  if (tid == 0) out[0] = (red[0]+red[1]+red[2]+red[3]) * (1.0f / 16777216.0f);
}

extern "C" void kernel_launch(void* const* d_in, const int* in_sizes, int n_in,
                              void* d_out, int out_size, void* d_ws, size_t ws_size,
                              hipStream_t stream) {
  const float* x_start   = (const float*)d_in[0];
  const int*   tarr      = (const int*)  d_in[1];
  const float* noise     = (const float*)d_in[2];
  const float* cond_src  = (const float*)d_in[3];
  const float* cond_tgt  = (const float*)d_in[4];
  const float* w_q       = (const float*)d_in[5];
  const float* w_k       = (const float*)d_in[6];
  const float* w_v       = (const float*)d_in[7];
  const float* sqrt_ac   = (const float*)d_in[8];
  const float* sqrt_omac = (const float*)d_in[9];
  float* out = (float*)d_out;
  char*  ws  = (char*)d_ws;

  // adaptive chunk size: need(cb) = 16 MiB (G+Wv) + cb*36880 (F+H+U+mask) + 4 KiB
  size_t CB;
  if      (ws_size >= 318902272ull) CB = 8192;
  else if (ws_size >= 167841792ull) CB = 4096;
  else if (ws_size >=  92311552ull) CB = 2048;
  else if (ws_size >=  54546432ull) CB = 1024;
  else return;  // < 52 MiB workspace: cannot run

  const size_t offG  = 0;
  const size_t offWv = 8388608;
  const size_t offF  = 16777216;
  const size_t szF   = CB * 16384;            // 4*CB*2048*2 bytes
  const size_t offH  = offF + szF;
  const size_t offU  = offH + szF;
  const size_t offMask = offU + CB * 4096;
  const size_t offLp   = offMask + CB * 16;

  unsigned short* G    = (unsigned short*)(ws + offG);
  unsigned short* WvBf = (unsigned short*)(ws + offWv);
  unsigned short* F    = (unsigned short*)(ws + offF);
  unsigned short* H    = (unsigned short*)(ws + offH);
  unsigned short* U    = (unsigned short*)(ws + offU);
  float* maskC = (float*)(ws + offMask);
  float* lpart = (float*)(ws + offLp);
  // setup-phase aliases (dead before chunk 0 writes F/H)
  unsigned short* WqT = F;
  unsigned short* WkT = H;

  transpose_cast<<<dim3(32, 32), 256, 0, stream>>>(w_q, WqT);
  transpose_cast<<<dim3(32, 32), 256, 0, stream>>>(w_k, WkT);
  cast_w<<<dim3(4096), 256, 0, stream>>>(w_v, WvBf);
  gemm_nt_bf16<<<dim3(16, 16), 256, 0, stream>>>(WqT, WkT, G);   // G = Wq^T Wk

  const int nchunks = NB / (int)CB;
  for (int ci = 0; ci < nchunks; ++ci) {
    const int b0 = ci * (int)CB;
    prep_tokens<<<dim3(NT, (int)CB), 256, 0, stream>>>(
        x_start, tarr, noise, cond_src, cond_tgt, sqrt_ac, sqrt_omac, F, maskC, b0);
    gemm_nt_256<<<dim3(ND/256, (NT*(int)CB)/256), 512, 0, stream>>>(F, G, H);  // H = F G^T
    attn_u<<<dim3((int)CB), 256, 0, stream>>>(F, H, maskC, U);
    gemm_nt_pred<<<dim3(16, (int)CB / 128), 256, 0, stream>>>(
        U, WvBf, out + 1, x_start, lpart, b0);                          // pred = U Wv^T
  }
  loss_final<<<dim3(1), 256, 0, stream>>>(lpart, out);
}

// Round 4
// 599.145 us; speedup vs baseline: 1.1311x; 1.0492x over previous
//
#include <hip/hip_runtime.h>
#include <math.h>

#define NB 8192
#define ND 2048
#define NT 4

using bf16x8 = __attribute__((ext_vector_type(8))) short;
using f32x4  = __attribute__((ext_vector_type(4))) float;

__device__ inline unsigned short f2bf(float f) {
  unsigned int u = __float_as_uint(f);
  u += 0x7FFFu + ((u >> 16) & 1u);           // RNE
  return (unsigned short)(u >> 16);
}
__device__ inline void unpack8(uint4 u, float* f) {
  f[0] = __uint_as_float(u.x << 16); f[1] = __uint_as_float(u.x & 0xFFFF0000u);
  f[2] = __uint_as_float(u.y << 16); f[3] = __uint_as_float(u.y & 0xFFFF0000u);
  f[4] = __uint_as_float(u.z << 16); f[5] = __uint_as_float(u.z & 0xFFFF0000u);
  f[6] = __uint_as_float(u.w << 16); f[7] = __uint_as_float(u.w & 0xFFFF0000u);
}

#define GL2LDS(g, l) __builtin_amdgcn_global_load_lds( \
    (const __attribute__((address_space(1))) void*)(g), \
    (__attribute__((address_space(3))) void*)(l), 16, 0, 0)

__device__ inline void waitv8() { asm volatile("s_waitcnt vmcnt(8)" ::: "memory"); }
__device__ inline void waitv4() { asm volatile("s_waitcnt vmcnt(4)" ::: "memory"); }
__device__ inline void waitv0() { asm volatile("s_waitcnt vmcnt(0)" ::: "memory"); }

// LDS bijection used by all GEMMs (per 16-row x 32-k bf16 subtile, 16B chunks):
//   (row r, k-chunk c) stored at slot r*4 + (c ^ ((r>>1)&3))
// Any 8 consecutive lanes of a ds_read_b128 (fixed c, r=0..7 or 8..15) hit all
// 8 slot%8 groups exactly once -> conflict-free in 8-lane phases. Writes via
// global_load_lds stay linear (also conflict-free); the permutation is applied
// to the GLOBAL source address instead (m173 pattern).

// ---------- transpose+cast: WT[d][e] = (bf16)W[e][d], 2048x2048 ---------------
__global__ __launch_bounds__(256) void transpose_cast(
    const float* __restrict__ W, unsigned short* __restrict__ WT)
{
  __shared__ float tile[64][65];
  const int t = threadIdx.x, r = t >> 2, c0 = (t & 3) * 16;
  const int bx = blockIdx.x * 64, by = blockIdx.y * 64;
  const float* src = W + (size_t)(by + r) * ND + bx + c0;
#pragma unroll
  for (int j = 0; j < 4; ++j) {
    float4 v = *reinterpret_cast<const float4*>(src + j * 4);
    tile[r][c0 + j*4 + 0] = v.x; tile[r][c0 + j*4 + 1] = v.y;
    tile[r][c0 + j*4 + 2] = v.z; tile[r][c0 + j*4 + 3] = v.w;
  }
  __syncthreads();
  unsigned int pk[8];
#pragma unroll
  for (int j = 0; j < 8; ++j) {
    unsigned int lo = f2bf(tile[c0 + 2*j    ][r]);
    unsigned int hi = f2bf(tile[c0 + 2*j + 1][r]);
    pk[j] = lo | (hi << 16);
  }
  unsigned short* dst = WT + (size_t)(bx + r) * ND + by + c0;
  *reinterpret_cast<uint4*>(dst)     = make_uint4(pk[0], pk[1], pk[2], pk[3]);
  *reinterpret_cast<uint4*>(dst + 8) = make_uint4(pk[4], pk[5], pk[6], pk[7]);
}

// ---------- plain cast f32 -> bf16 (row-major copy) ---------------------------
__global__ __launch_bounds__(256) void cast_w(const float* __restrict__ w,
                                              unsigned short* __restrict__ o) {
  const size_t i4 = ((size_t)blockIdx.x * 256 + threadIdx.x) * 4;
  float4 f = *reinterpret_cast<const float4*>(w + i4);
  ushort4 r;
  r.x = f2bf(f.x); r.y = f2bf(f.y); r.z = f2bf(f.z); r.w = f2bf(f.w);
  *reinterpret_cast<ushort4*>(o + i4) = r;
}

// ---------- tokens + mask + LayerNorm -> F chunk (bf16) -----------------------
__global__ __launch_bounds__(256) void prep_tokens(
    const float* __restrict__ x_start, const int* __restrict__ tarr,
    const float* __restrict__ noise, const float* __restrict__ cond_src,
    const float* __restrict__ cond_tgt, const float* __restrict__ sqrt_ac,
    const float* __restrict__ sqrt_omac, unsigned short* __restrict__ F,
    float* __restrict__ maskf, int b0)
{
  const int cb = blockIdx.y, tok = blockIdx.x, tid = threadIdx.x;
  const int b = b0 + cb;
  const int e0 = tid * 8;
  float v[8];
  if (tok == 0) {
    const int tb = tarr[b];
    const float sa = sqrt_ac[tb], so = sqrt_omac[tb];
    const float4* xs = reinterpret_cast<const float4*>(x_start + (size_t)b * ND + e0);
    const float4* ns = reinterpret_cast<const float4*>(noise + (size_t)b * ND + e0);
    float4 x0 = xs[0], x1 = xs[1], n0 = ns[0], n1 = ns[1];
    v[0] = sa*x0.x + so*n0.x; v[1] = sa*x0.y + so*n0.y;
    v[2] = sa*x0.z + so*n0.z; v[3] = sa*x0.w + so*n0.w;
    v[4] = sa*x1.x + so*n1.x; v[5] = sa*x1.y + so*n1.y;
    v[6] = sa*x1.z + so*n1.z; v[7] = sa*x1.w + so*n1.w;
  } else if (tok == 1) {
    const float tf = (float)tarr[b];
    const float cc = -9.210340371976184f / 1023.0f;  // -ln(10000)/(half-1)
#pragma unroll
    for (int j = 0; j < 8; ++j) {
      int e = e0 + j;
      int i = (e < 1024) ? e : (e - 1024);
      float a = tf * expf((float)i * cc);
      v[j] = (e < 1024) ? sinf(a) : cosf(a);
    }
  } else {
    const float* src = (tok == 2) ? cond_src : cond_tgt;
    const float4* ps = reinterpret_cast<const float4*>(src + (size_t)b * ND + e0);
    float4 a0 = ps[0], a1 = ps[1];
    v[0]=a0.x; v[1]=a0.y; v[2]=a0.z; v[3]=a0.w;
    v[4]=a1.x; v[5]=a1.y; v[6]=a1.z; v[7]=a1.w;
  }
  float s = 0.f, s2 = 0.f, sab = 0.f;
#pragma unroll
  for (int j = 0; j < 8; ++j) { s += v[j]; s2 += v[j]*v[j]; sab += fabsf(v[j]); }
#pragma unroll
  for (int o = 32; o > 0; o >>= 1) {
    s += __shfl_xor(s, o); s2 += __shfl_xor(s2, o); sab += __shfl_xor(sab, o);
  }
  __shared__ float red[12];
  const int lane = tid & 63, wid = tid >> 6;
  if (lane == 0) { red[wid*3+0] = s; red[wid*3+1] = s2; red[wid*3+2] = sab; }
  __syncthreads();
  s   = red[0] + red[3] + red[6] + red[9];
  s2  = red[1] + red[4] + red[7] + red[10];
  sab = red[2] + red[5] + red[8] + red[11];
  const float mu  = s * (1.0f / ND);
  const float var = s2 * (1.0f / ND) - mu * mu;
  const float rs  = rsqrtf(var + 1e-5f);
  if (tid == 0) maskf[(size_t)cb*NT + tok] = (sab > 0.0f) ? 1.0f : 0.0f;
  unsigned int pk[4];
#pragma unroll
  for (int j = 0; j < 4; ++j) {
    unsigned int lo = f2bf((v[2*j]   - mu) * rs);
    unsigned int hi = f2bf((v[2*j+1] - mu) * rs);
    pk[j] = lo | (hi << 16);
  }
  *reinterpret_cast<uint4*>(F + ((size_t)cb*NT + tok) * ND + e0) =
      make_uint4(pk[0], pk[1], pk[2], pk[3]);
}

// ---------- 128^2 GEMM core (swizzled LDS): C=A*B^T, bf16 out -----------------
__global__ __launch_bounds__(256) void gemm_nt_bf16(
    const unsigned short* __restrict__ A, const unsigned short* __restrict__ B,
    unsigned short* __restrict__ C)
{
  constexpr int K = ND;
  __shared__ unsigned short As[128*32];
  __shared__ unsigned short Bs[128*32];
  const int tid = threadIdx.x;
  const int lane = tid & 63, wid = tid >> 6;
  const int wm = wid >> 1, wn = wid & 1;
  const size_t arow0 = (size_t)blockIdx.y * 128;
  const size_t bcol0 = (size_t)blockIdx.x * 128;
  f32x4 acc[4][4] = {};
  const int row0 = tid >> 2, row1 = row0 + 64;
  const int kc = (((tid & 3) ^ ((tid >> 3) & 3))) * 8;   // swizzled source chunk
  const unsigned short* ga0 = A + (arow0 + row0) * K + kc;
  const unsigned short* ga1 = A + (arow0 + row1) * K + kc;
  const unsigned short* gb0 = B + (bcol0 + row0) * K + kc;
  const unsigned short* gb1 = B + (bcol0 + row1) * K + kc;
  char* lAs = (char*)As; char* lBs = (char*)Bs;
  const int lo0 = wid * 1024, lo1 = 4096 + wid * 1024;
  const int ar = (lane & 15);
  const int ko = ((lane >> 4) ^ ((lane >> 1) & 3)) * 8;  // swizzled read chunk
  for (int k0 = 0; k0 < K; k0 += 32) {
    GL2LDS(ga0 + k0, lAs + lo0);
    GL2LDS(ga1 + k0, lAs + lo1);
    GL2LDS(gb0 + k0, lBs + lo0);
    GL2LDS(gb1 + k0, lBs + lo1);
    __syncthreads();
    bf16x8 af[4], bfr[4];
#pragma unroll
    for (int mi = 0; mi < 4; ++mi)
      af[mi] = *reinterpret_cast<const bf16x8*>(&As[(wm*64 + mi*16 + ar)*32 + ko]);
#pragma unroll
    for (int ni = 0; ni < 4; ++ni)
      bfr[ni] = *reinterpret_cast<const bf16x8*>(&Bs[(wn*64 + ni*16 + ar)*32 + ko]);
#pragma unroll
    for (int mi = 0; mi < 4; ++mi)
#pragma unroll
      for (int ni = 0; ni < 4; ++ni)
        acc[mi][ni] = __builtin_amdgcn_mfma_f32_16x16x32_bf16(af[mi], bfr[ni], acc[mi][ni], 0, 0, 0);
    __syncthreads();
  }
#pragma unroll
  for (int mi = 0; mi < 4; ++mi)
#pragma unroll
    for (int ni = 0; ni < 4; ++ni) {
      const size_t col = bcol0 + wn*64 + ni*16 + (lane & 15);
#pragma unroll
      for (int r = 0; r < 4; ++r) {
        const size_t row = arow0 + wm*64 + mi*16 + (lane >> 4)*4 + r;
        C[row * ND + col] = f2bf(acc[mi][ni][r]);
      }
    }
}

// ---------- 256^2 tile, BK=32, ring-4 LDS, counted-vmcnt, swizzled, XCD -------
__global__ __launch_bounds__(512, 2) void gemm_nt_256(
    const unsigned short* __restrict__ A, const unsigned short* __restrict__ B,
    unsigned short* __restrict__ C)
{
  constexpr int K = 2048;
  constexpr int NTILE = K / 32;  // 64
  __shared__ unsigned short lds[65536];  // 128 KiB: 4 rings x (A 16K + B 16K)
  const int tid = threadIdx.x;
  const int lane = tid & 63, wid = tid >> 6;
  const int wm = wid >> 2, wn = wid & 3;

  // XCD-aware swizzle: block o -> XCD o%8 (HW round-robin); give each XCD a
  // contiguous range so concurrent blocks share A-panels in its private L2.
  const int GX = (int)gridDim.x;                 // 8 (N/256)
  const int nwg = GX * (int)gridDim.y;
  const int o = (int)blockIdx.y * GX + (int)blockIdx.x;
  const int swz = (o & 7) * (nwg >> 3) + (o >> 3);
  const int bx = swz % GX, by = swz / GX;

  const size_t arow0 = (size_t)by * 256;
  const size_t bcol0 = (size_t)bx * 256;
  char* ldsb = (char*)lds;

  // ---- staging: slot s holds (r=s>>2, c=(s&3)^((r>>1)&3)) ----
  const int s0 = wid*64 + lane, s1 = s0 + 512;
  const int rS0 = s0 >> 2, cS0 = (s0 & 3) ^ ((rS0 >> 1) & 3);
  const int rS1 = s1 >> 2, cS1 = (s1 & 3) ^ ((rS1 >> 1) & 3);
  const unsigned short* gA0 = A + (arow0 + rS0) * K + cS0*8;
  const unsigned short* gA1 = A + (arow0 + rS1) * K + cS1*8;
  const unsigned short* gB0 = B + (bcol0 + rS0) * K + cS0*8;
  const unsigned short* gB1 = B + (bcol0 + rS1) * K + cS1*8;
  const int ldsw0 = wid * 1024;          // round-0 uniform base (bytes)
  const int ldsw1 = 8192 + wid * 1024;   // round-1

#define STAGE_A(tt) { const int q_ = (tt)&3, k_ = (tt)*32;                 \
    GL2LDS(gA0 + k_, ldsb + q_*32768 + ldsw0);                             \
    GL2LDS(gA1 + k_, ldsb + q_*32768 + ldsw1); }
#define STAGE_B(tt) { const int q_ = (tt)&3, k_ = (tt)*32;                 \
    GL2LDS(gB0 + k_, ldsb + q_*32768 + 16384 + ldsw0);                     \
    GL2LDS(gB1 + k_, ldsb + q_*32768 + 16384 + ldsw1); }

  // ---- fragment read offset (bytes, within A or B region of a ring) ----
  const int lo16 = ((lane & 15) * 4 + ((lane >> 4) ^ ((lane >> 1) & 3))) * 16;

  f32x4 acc[8][4] = {};
  bf16x8 af[4], bfr[4];

  // prologue: stage tiles 0,1,2; wait tile 0 (8 loads of tiles 1,2 in flight)
  STAGE_A(0); STAGE_B(0);
  STAGE_A(1); STAGE_B(1);
  STAGE_A(2); STAGE_B(2);
  waitv8();
  __builtin_amdgcn_s_barrier();

  for (int t = 0; t < NTILE; ++t) {
    const char* bA = ldsb + (t & 3) * 32768;
    const char* bB = bA + 16384;
    // ---- phase 0: read A-half0 + all B frags; stage A of t+3 ----
#pragma unroll
    for (int mi = 0; mi < 4; ++mi)
      af[mi] = *reinterpret_cast<const bf16x8*>(bA + wm*8192 + mi*1024 + lo16);
#pragma unroll
    for (int ni = 0; ni < 4; ++ni)
      bfr[ni] = *reinterpret_cast<const bf16x8*>(bB + wn*4096 + ni*1024 + lo16);
    if (t < NTILE - 3) STAGE_A(t + 3);
    __builtin_amdgcn_s_barrier();
    __builtin_amdgcn_s_setprio(1);
#pragma unroll
    for (int mi = 0; mi < 4; ++mi)
#pragma unroll
      for (int ni = 0; ni < 4; ++ni)
        acc[mi][ni] = __builtin_amdgcn_mfma_f32_16x16x32_bf16(af[mi], bfr[ni], acc[mi][ni], 0, 0, 0);
    __builtin_amdgcn_s_setprio(0);
    __builtin_amdgcn_s_barrier();
    // ---- phase 1: read A-half1 (B frags still live); stage B of t+3 ----
#pragma unroll
    for (int mi = 0; mi < 4; ++mi)
      af[mi] = *reinterpret_cast<const bf16x8*>(bA + wm*8192 + (mi+4)*1024 + lo16);
    if (t < NTILE - 3) STAGE_B(t + 3);
    __builtin_amdgcn_s_barrier();
    __builtin_amdgcn_s_setprio(1);
#pragma unroll
    for (int mi = 0; mi < 4; ++mi)
#pragma unroll
      for (int ni = 0; ni < 4; ++ni)
        acc[mi+4][ni] = __builtin_amdgcn_mfma_f32_16x16x32_bf16(af[mi], bfr[ni], acc[mi+4][ni], 0, 0, 0);
    __builtin_amdgcn_s_setprio(0);
    // ---- boundary: counted wait -> tile t+1 resident; then barrier ----
    if (t < NTILE - 3)       waitv8();
    else if (t == NTILE - 3) waitv4();
    else if (t == NTILE - 2) waitv0();
    __builtin_amdgcn_s_barrier();
  }
#undef STAGE_A
#undef STAGE_B

  // epilogue: C/D layout col=lane&15, row=(lane>>4)*4+reg
#pragma unroll
  for (int mi = 0; mi < 8; ++mi)
#pragma unroll
    for (int ni = 0; ni < 4; ++ni) {
      const size_t col = bcol0 + wn*64 + ni*16 + (lane & 15);
#pragma unroll
      for (int r = 0; r < 4; ++r) {
        const size_t row = arow0 + wm*128 + mi*16 + (lane >> 4)*4 + r;
        C[row * 2048 + col] = f2bf(acc[mi][ni][r]);
      }
    }
}

// ---------- pred GEMM (swizzled LDS): f32 out to d_out(+1) + loss partials ----
__global__ __launch_bounds__(256) void gemm_nt_pred(
    const unsigned short* __restrict__ A, const unsigned short* __restrict__ B,
    float* __restrict__ outp /* = out+1 */, const float* __restrict__ x_start,
    float* __restrict__ lpart, int b0)
{
  constexpr int K = ND;
  __shared__ unsigned short As[128*32];
  __shared__ unsigned short Bs[128*32];
  __shared__ float r2[4];
  const int tid = threadIdx.x;
  const int lane = tid & 63, wid = tid >> 6;
  const int wm = wid >> 1, wn = wid & 1;
  const size_t arow0 = (size_t)blockIdx.y * 128;
  const size_t bcol0 = (size_t)blockIdx.x * 128;
  f32x4 acc[4][4] = {};
  const int row0 = tid >> 2, row1 = row0 + 64;
  const int kc = (((tid & 3) ^ ((tid >> 3) & 3))) * 8;
  const unsigned short* ga0 = A + (arow0 + row0) * K + kc;
  const unsigned short* ga1 = A + (arow0 + row1) * K + kc;
  const unsigned short* gb0 = B + (bcol0 + row0) * K + kc;
  const unsigned short* gb1 = B + (bcol0 + row1) * K + kc;
  char* lAs = (char*)As; char* lBs = (char*)Bs;
  const int lo0 = wid * 1024, lo1 = 4096 + wid * 1024;
  const int ar = (lane & 15);
  const int ko = ((lane >> 4) ^ ((lane >> 1) & 3)) * 8;
  for (int k0 = 0; k0 < K; k0 += 32) {
    GL2LDS(ga0 + k0, lAs + lo0);
    GL2LDS(ga1 + k0, lAs + lo1);
    GL2LDS(gb0 + k0, lBs + lo0);
    GL2LDS(gb1 + k0, lBs + lo1);
    __syncthreads();
    bf16x8 af[4], bfr[4];
#pragma unroll
    for (int mi = 0; mi < 4; ++mi)
      af[mi] = *reinterpret_cast<const bf16x8*>(&As[(wm*64 + mi*16 + ar)*32 + ko]);
#pragma unroll
    for (int ni = 0; ni < 4; ++ni)
      bfr[ni] = *reinterpret_cast<const bf16x8*>(&Bs[(wn*64 + ni*16 + ar)*32 + ko]);
#pragma unroll
    for (int mi = 0; mi < 4; ++mi)
#pragma unroll
      for (int ni = 0; ni < 4; ++ni)
        acc[mi][ni] = __builtin_amdgcn_mfma_f32_16x16x32_bf16(af[mi], bfr[ni], acc[mi][ni], 0, 0, 0);
    __syncthreads();
  }
  float sse = 0.f;
#pragma unroll
  for (int mi = 0; mi < 4; ++mi)
#pragma unroll
    for (int ni = 0; ni < 4; ++ni) {
      const size_t col = bcol0 + wn*64 + ni*16 + (lane & 15);
#pragma unroll
      for (int r = 0; r < 4; ++r) {
        const size_t row = arow0 + wm*64 + mi*16 + (lane >> 4)*4 + r;  // chunk-local b
        const size_t gb  = (size_t)b0 + row;                           // global b
        const float p = acc[mi][ni][r];
        outp[gb * ND + col] = p;
        const float d = p - x_start[gb * ND + col];
        sse += d * d;
      }
    }
#pragma unroll
  for (int o = 32; o > 0; o >>= 1) sse += __shfl_xor(sse, o);
  if (lane == 0) r2[wid] = sse;
  __syncthreads();
  if (tid == 0) {
    const int slot = ((b0 >> 7) + (int)blockIdx.y) * 16 + (int)blockIdx.x;
    lpart[slot] = r2[0] + r2[1] + r2[2] + r2[3];
  }
}

// ---------- per-group: logits from F,H -> softmax -> u = sum_j c_j f_j --------
__global__ __launch_bounds__(256) void attn_u(
    const unsigned short* __restrict__ F, const unsigned short* __restrict__ H,
    const float* __restrict__ maskf, unsigned short* __restrict__ U)
{
  const int cb = blockIdx.x, tid = threadIdx.x;
  const int e0 = tid * 8, lane = tid & 63, wid = tid >> 6;
  __shared__ float red[64];
  float f[4][8], h[4][8];
#pragma unroll
  for (int i = 0; i < 4; ++i) {
    unpack8(*reinterpret_cast<const uint4*>(F + ((size_t)cb*4 + i)*ND + e0), f[i]);
    unpack8(*reinterpret_cast<const uint4*>(H + ((size_t)cb*4 + i)*ND + e0), h[i]);
  }
  float part[16];
#pragma unroll
  for (int i = 0; i < 4; ++i)
#pragma unroll
    for (int j = 0; j < 4; ++j) {
      float p = 0.f;
#pragma unroll
      for (int r = 0; r < 8; ++r) p += f[i][r] * h[j][r];
      part[i*4+j] = p;
    }
#pragma unroll
  for (int idx = 0; idx < 16; ++idx)
#pragma unroll
    for (int o = 32; o > 0; o >>= 1) part[idx] += __shfl_xor(part[idx], o);
  if (lane == 0) {
#pragma unroll
    for (int idx = 0; idx < 16; ++idx) red[wid*16 + idx] = part[idx];
  }
  __syncthreads();
  float lg[16];
#pragma unroll
  for (int idx = 0; idx < 16; ++idx)
    lg[idx] = red[idx] + red[16+idx] + red[32+idx] + red[48+idx];

  const float scale = 0.022097086912079608f;  // 2048^-0.5
  float m[4];
#pragma unroll
  for (int j = 0; j < 4; ++j) m[j] = maskf[(size_t)cb*NT + j];
  const float denom = fmaxf(m[0]+m[1]+m[2]+m[3], 1.0f);
  float c[4] = {0.f, 0.f, 0.f, 0.f};
#pragma unroll
  for (int i = 0; i < 4; ++i) {
    float x[4];
#pragma unroll
    for (int j = 0; j < 4; ++j) x[j] = (m[j] > 0.f) ? lg[i*4+j]*scale : -1e9f;
    const float mx = fmaxf(fmaxf(x[0],x[1]), fmaxf(x[2],x[3]));
    float p[4], sum = 0.f;
#pragma unroll
    for (int j = 0; j < 4; ++j) { p[j] = expf(x[j]-mx); sum += p[j]; }
    const float w = m[i] / (sum * denom);
#pragma unroll
    for (int j = 0; j < 4; ++j) c[j] += p[j] * w;
  }
  unsigned int pk[4];
#pragma unroll
  for (int jj = 0; jj < 4; ++jj) {
    float ulo = c[0]*f[0][2*jj]   + c[1]*f[1][2*jj]   + c[2]*f[2][2*jj]   + c[3]*f[3][2*jj];
    float uhi = c[0]*f[0][2*jj+1] + c[1]*f[1][2*jj+1] + c[2]*f[2][2*jj+1] + c[3]*f[3][2*jj+1];
    pk[jj] = (unsigned int)f2bf(ulo) | ((unsigned int)f2bf(uhi) << 16);
  }
  *reinterpret_cast<uint4*>(U + (size_t)cb*ND + e0) = make_uint4(pk[0],pk[1],pk[2],pk[3]);
}

// ---------- deterministic loss reduce (1024 fixed slots) ----------------------
__global__ __launch_bounds__(256) void loss_final(const float* __restrict__ lpart,
                                                  float* __restrict__ out) {
  const int tid = threadIdx.x;
  float s = 0.f;
  for (int i = tid; i < 1024; i += 256) s += lpart[i];
#pragma unroll
  for (int o = 32; o > 0; o >>= 1) s += __shfl_xor(s, o);
  __shared__ float red[4];
  const int lane = tid & 63, wid = tid >> 6;
  if (lane == 0) red[wid] = s;
  __syncthreads();
  if (tid == 0) out[0] = (red[0]+red[1]+red[2]+red[3]) * (1.0f / 16777216.0f);
}

extern "C" void kernel_launch(void* const* d_in, const int* in_sizes, int n_in,
                              void* d_out, int out_size, void* d_ws, size_t ws_size,
                              hipStream_t stream) {
  const float* x_start   = (const float*)d_in[0];
  const int*   tarr      = (const int*)  d_in[1];
  const float* noise     = (const float*)d_in[2];
  const float* cond_src  = (const float*)d_in[3];
  const float* cond_tgt  = (const float*)d_in[4];
  const float* w_q       = (const float*)d_in[5];
  const float* w_k       = (const float*)d_in[6];
  const float* w_v       = (const float*)d_in[7];
  const float* sqrt_ac   = (const float*)d_in[8];
  const float* sqrt_omac = (const float*)d_in[9];
  float* out = (float*)d_out;
  char*  ws  = (char*)d_ws;

  // adaptive chunk size: need(cb) = 16 MiB (G+Wv) + cb*36880 (F+H+U+mask) + 4 KiB
  size_t CB;
  if      (ws_size >= 318902272ull) CB = 8192;
  else if (ws_size >= 167841792ull) CB = 4096;
  else if (ws_size >=  92311552ull) CB = 2048;
  else if (ws_size >=  54546432ull) CB = 1024;
  else return;  // < 52 MiB workspace: cannot run

  const size_t offG  = 0;
  const size_t offWv = 8388608;
  const size_t offF  = 16777216;
  const size_t szF   = CB * 16384;            // 4*CB*2048*2 bytes
  const size_t offH  = offF + szF;
  const size_t offU  = offH + szF;
  const size_t offMask = offU + CB * 4096;
  const size_t offLp   = offMask + CB * 16;

  unsigned short* G    = (unsigned short*)(ws + offG);
  unsigned short* WvBf = (unsigned short*)(ws + offWv);
  unsigned short* F    = (unsigned short*)(ws + offF);
  unsigned short* H    = (unsigned short*)(ws + offH);
  unsigned short* U    = (unsigned short*)(ws + offU);
  float* maskC = (float*)(ws + offMask);
  float* lpart = (float*)(ws + offLp);
  // setup-phase aliases (dead before chunk 0 writes F/H)
  unsigned short* WqT = F;
  unsigned short* WkT = H;

  transpose_cast<<<dim3(32, 32), 256, 0, stream>>>(w_q, WqT);
  transpose_cast<<<dim3(32, 32), 256, 0, stream>>>(w_k, WkT);
  cast_w<<<dim3(4096), 256, 0, stream>>>(w_v, WvBf);
  gemm_nt_bf16<<<dim3(16, 16), 256, 0, stream>>>(WqT, WkT, G);   // G = Wq^T Wk

  const int nchunks = NB / (int)CB;
  for (int ci = 0; ci < nchunks; ++ci) {
    const int b0 = ci * (int)CB;
    prep_tokens<<<dim3(NT, (int)CB), 256, 0, stream>>>(
        x_start, tarr, noise, cond_src, cond_tgt, sqrt_ac, sqrt_omac, F, maskC, b0);
    gemm_nt_256<<<dim3(ND/256, (NT*(int)CB)/256), 512, 0, stream>>>(F, G, H);  // H = F G^T
    attn_u<<<dim3((int)CB), 256, 0, stream>>>(F, H, maskC, U);
    gemm_nt_pred<<<dim3(16, (int)CB / 128), 256, 0, stream>>>(
        U, WvBf, out + 1, x_start, lpart, b0);                          // pred = U Wv^T
  }
  loss_final<<<dim3(1), 256, 0, stream>>>(lpart, out);
}

// Round 5
// 593.467 us; speedup vs baseline: 1.1419x; 1.0096x over previous
//
#include <hip/hip_runtime.h>
#include <math.h>

#define NB 8192
#define ND 2048
#define NT 4

using bf16x8 = __attribute__((ext_vector_type(8))) short;
using f32x4  = __attribute__((ext_vector_type(4))) float;

__device__ inline unsigned short f2bf(float f) {
  unsigned int u = __float_as_uint(f);
  u += 0x7FFFu + ((u >> 16) & 1u);           // RNE
  return (unsigned short)(u >> 16);
}
__device__ inline void unpack8(uint4 u, float* f) {
  f[0] = __uint_as_float(u.x << 16); f[1] = __uint_as_float(u.x & 0xFFFF0000u);
  f[2] = __uint_as_float(u.y << 16); f[3] = __uint_as_float(u.y & 0xFFFF0000u);
  f[4] = __uint_as_float(u.z << 16); f[5] = __uint_as_float(u.z & 0xFFFF0000u);
  f[6] = __uint_as_float(u.w << 16); f[7] = __uint_as_float(u.w & 0xFFFF0000u);
}

#define GL2LDS(g, l) __builtin_amdgcn_global_load_lds( \
    (const __attribute__((address_space(1))) void*)(g), \
    (__attribute__((address_space(3))) void*)(l), 16, 0, 0)

__device__ inline void waitv8() { asm volatile("s_waitcnt vmcnt(8)" ::: "memory"); }
__device__ inline void waitv4() { asm volatile("s_waitcnt vmcnt(4)" ::: "memory"); }
__device__ inline void waitv0() { asm volatile("s_waitcnt vmcnt(0)" ::: "memory"); }

// LDS bijection used by all GEMMs (per 16-row x 32-k bf16 subtile, 16B chunks):
//   (row r, k-chunk c) stored at slot r*4 + (c ^ ((r>>1)&3))
// Any 8 consecutive lanes of a ds_read_b128 (fixed c, r=0..7 or 8..15) hit all
// 8 slot%8 groups exactly once -> conflict-free (verified: conflicts==0 in r4).
// Writes via global_load_lds stay linear; the permutation is applied to the
// GLOBAL source address instead (m173 pattern).

// ---------- transpose+cast: WT[d][e] = (bf16)W[e][d], 2048x2048 ---------------
__global__ __launch_bounds__(256) void transpose_cast(
    const float* __restrict__ W, unsigned short* __restrict__ WT)
{
  __shared__ float tile[64][65];
  const int t = threadIdx.x, r = t >> 2, c0 = (t & 3) * 16;
  const int bx = blockIdx.x * 64, by = blockIdx.y * 64;
  const float* src = W + (size_t)(by + r) * ND + bx + c0;
#pragma unroll
  for (int j = 0; j < 4; ++j) {
    float4 v = *reinterpret_cast<const float4*>(src + j * 4);
    tile[r][c0 + j*4 + 0] = v.x; tile[r][c0 + j*4 + 1] = v.y;
    tile[r][c0 + j*4 + 2] = v.z; tile[r][c0 + j*4 + 3] = v.w;
  }
  __syncthreads();
  unsigned int pk[8];
#pragma unroll
  for (int j = 0; j < 8; ++j) {
    unsigned int lo = f2bf(tile[c0 + 2*j    ][r]);
    unsigned int hi = f2bf(tile[c0 + 2*j + 1][r]);
    pk[j] = lo | (hi << 16);
  }
  unsigned short* dst = WT + (size_t)(bx + r) * ND + by + c0;
  *reinterpret_cast<uint4*>(dst)     = make_uint4(pk[0], pk[1], pk[2], pk[3]);
  *reinterpret_cast<uint4*>(dst + 8) = make_uint4(pk[4], pk[5], pk[6], pk[7]);
}

// ---------- plain cast f32 -> bf16 (row-major copy) ---------------------------
__global__ __launch_bounds__(256) void cast_w(const float* __restrict__ w,
                                              unsigned short* __restrict__ o) {
  const size_t i4 = ((size_t)blockIdx.x * 256 + threadIdx.x) * 4;
  float4 f = *reinterpret_cast<const float4*>(w + i4);
  ushort4 r;
  r.x = f2bf(f.x); r.y = f2bf(f.y); r.z = f2bf(f.z); r.w = f2bf(f.w);
  *reinterpret_cast<ushort4*>(o + i4) = r;
}

// ---------- tokens + mask + LayerNorm -> F chunk (bf16) -----------------------
__global__ __launch_bounds__(256) void prep_tokens(
    const float* __restrict__ x_start, const int* __restrict__ tarr,
    const float* __restrict__ noise, const float* __restrict__ cond_src,
    const float* __restrict__ cond_tgt, const float* __restrict__ sqrt_ac,
    const float* __restrict__ sqrt_omac, unsigned short* __restrict__ F,
    float* __restrict__ maskf, int b0)
{
  const int cb = blockIdx.y, tok = blockIdx.x, tid = threadIdx.x;
  const int b = b0 + cb;
  const int e0 = tid * 8;
  float v[8];
  if (tok == 0) {
    const int tb = tarr[b];
    const float sa = sqrt_ac[tb], so = sqrt_omac[tb];
    const float4* xs = reinterpret_cast<const float4*>(x_start + (size_t)b * ND + e0);
    const float4* ns = reinterpret_cast<const float4*>(noise + (size_t)b * ND + e0);
    float4 x0 = xs[0], x1 = xs[1], n0 = ns[0], n1 = ns[1];
    v[0] = sa*x0.x + so*n0.x; v[1] = sa*x0.y + so*n0.y;
    v[2] = sa*x0.z + so*n0.z; v[3] = sa*x0.w + so*n0.w;
    v[4] = sa*x1.x + so*n1.x; v[5] = sa*x1.y + so*n1.y;
    v[6] = sa*x1.z + so*n1.z; v[7] = sa*x1.w + so*n1.w;
  } else if (tok == 1) {
    const float tf = (float)tarr[b];
    const float cc = -9.210340371976184f / 1023.0f;  // -ln(10000)/(half-1)
#pragma unroll
    for (int j = 0; j < 8; ++j) {
      int e = e0 + j;
      int i = (e < 1024) ? e : (e - 1024);
      float a = tf * expf((float)i * cc);
      v[j] = (e < 1024) ? sinf(a) : cosf(a);
    }
  } else {
    const float* src = (tok == 2) ? cond_src : cond_tgt;
    const float4* ps = reinterpret_cast<const float4*>(src + (size_t)b * ND + e0);
    float4 a0 = ps[0], a1 = ps[1];
    v[0]=a0.x; v[1]=a0.y; v[2]=a0.z; v[3]=a0.w;
    v[4]=a1.x; v[5]=a1.y; v[6]=a1.z; v[7]=a1.w;
  }
  float s = 0.f, s2 = 0.f, sab = 0.f;
#pragma unroll
  for (int j = 0; j < 8; ++j) { s += v[j]; s2 += v[j]*v[j]; sab += fabsf(v[j]); }
#pragma unroll
  for (int o = 32; o > 0; o >>= 1) {
    s += __shfl_xor(s, o); s2 += __shfl_xor(s2, o); sab += __shfl_xor(sab, o);
  }
  __shared__ float red[12];
  const int lane = tid & 63, wid = tid >> 6;
  if (lane == 0) { red[wid*3+0] = s; red[wid*3+1] = s2; red[wid*3+2] = sab; }
  __syncthreads();
  s   = red[0] + red[3] + red[6] + red[9];
  s2  = red[1] + red[4] + red[7] + red[10];
  sab = red[2] + red[5] + red[8] + red[11];
  const float mu  = s * (1.0f / ND);
  const float var = s2 * (1.0f / ND) - mu * mu;
  const float rs  = rsqrtf(var + 1e-5f);
  if (tid == 0) maskf[(size_t)cb*NT + tok] = (sab > 0.0f) ? 1.0f : 0.0f;
  unsigned int pk[4];
#pragma unroll
  for (int j = 0; j < 4; ++j) {
    unsigned int lo = f2bf((v[2*j]   - mu) * rs);
    unsigned int hi = f2bf((v[2*j+1] - mu) * rs);
    pk[j] = lo | (hi << 16);
  }
  *reinterpret_cast<uint4*>(F + ((size_t)cb*NT + tok) * ND + e0) =
      make_uint4(pk[0], pk[1], pk[2], pk[3]);
}

// ---------- 128^2 GEMM core (swizzled LDS): C=A*B^T, bf16 out -----------------
__global__ __launch_bounds__(256) void gemm_nt_bf16(
    const unsigned short* __restrict__ A, const unsigned short* __restrict__ B,
    unsigned short* __restrict__ C)
{
  constexpr int K = ND;
  __shared__ unsigned short As[128*32];
  __shared__ unsigned short Bs[128*32];
  const int tid = threadIdx.x;
  const int lane = tid & 63, wid = tid >> 6;
  const int wm = wid >> 1, wn = wid & 1;
  const size_t arow0 = (size_t)blockIdx.y * 128;
  const size_t bcol0 = (size_t)blockIdx.x * 128;
  f32x4 acc[4][4] = {};
  const int row0 = tid >> 2, row1 = row0 + 64;
  const int kc = (((tid & 3) ^ ((tid >> 3) & 3))) * 8;   // swizzled source chunk
  const unsigned short* ga0 = A + (arow0 + row0) * K + kc;
  const unsigned short* ga1 = A + (arow0 + row1) * K + kc;
  const unsigned short* gb0 = B + (bcol0 + row0) * K + kc;
  const unsigned short* gb1 = B + (bcol0 + row1) * K + kc;
  char* lAs = (char*)As; char* lBs = (char*)Bs;
  const int lo0 = wid * 1024, lo1 = 4096 + wid * 1024;
  const int ar = (lane & 15);
  const int ko = ((lane >> 4) ^ ((lane >> 1) & 3)) * 8;  // swizzled read chunk
  for (int k0 = 0; k0 < K; k0 += 32) {
    GL2LDS(ga0 + k0, lAs + lo0);
    GL2LDS(ga1 + k0, lAs + lo1);
    GL2LDS(gb0 + k0, lBs + lo0);
    GL2LDS(gb1 + k0, lBs + lo1);
    __syncthreads();
    bf16x8 af[4], bfr[4];
#pragma unroll
    for (int mi = 0; mi < 4; ++mi)
      af[mi] = *reinterpret_cast<const bf16x8*>(&As[(wm*64 + mi*16 + ar)*32 + ko]);
#pragma unroll
    for (int ni = 0; ni < 4; ++ni)
      bfr[ni] = *reinterpret_cast<const bf16x8*>(&Bs[(wn*64 + ni*16 + ar)*32 + ko]);
#pragma unroll
    for (int mi = 0; mi < 4; ++mi)
#pragma unroll
      for (int ni = 0; ni < 4; ++ni)
        acc[mi][ni] = __builtin_amdgcn_mfma_f32_16x16x32_bf16(af[mi], bfr[ni], acc[mi][ni], 0, 0, 0);
    __syncthreads();
  }
#pragma unroll
  for (int mi = 0; mi < 4; ++mi)
#pragma unroll
    for (int ni = 0; ni < 4; ++ni) {
      const size_t col = bcol0 + wn*64 + ni*16 + (lane & 15);
#pragma unroll
      for (int r = 0; r < 4; ++r) {
        const size_t row = arow0 + wm*64 + mi*16 + (lane >> 4)*4 + r;
        C[row * ND + col] = f2bf(acc[mi][ni][r]);
      }
    }
}

// ---------- 256^2 tile, BK=32, ring-4 LDS, counted-vmcnt, 1 barrier/tile ------
__global__ __launch_bounds__(512, 2) void gemm_nt_256(
    const unsigned short* __restrict__ A, const unsigned short* __restrict__ B,
    unsigned short* __restrict__ C)
{
  constexpr int K = 2048;
  constexpr int NTILE = K / 32;  // 64
  __shared__ unsigned short lds[65536];  // 128 KiB: 4 rings x (A 16K + B 16K)
  const int tid = threadIdx.x;
  const int lane = tid & 63, wid = tid >> 6;
  const int wm = wid >> 2, wn = wid & 3;

  // XCD-aware swizzle: block o -> XCD o%8 (HW round-robin); give each XCD a
  // contiguous range so concurrent blocks share A-panels in its private L2.
  const int GX = (int)gridDim.x;                 // 8 (N/256)
  const int nwg = GX * (int)gridDim.y;
  const int o = (int)blockIdx.y * GX + (int)blockIdx.x;
  const int swz = (o & 7) * (nwg >> 3) + (o >> 3);
  const int bx = swz % GX, by = swz / GX;

  const size_t arow0 = (size_t)by * 256;
  const size_t bcol0 = (size_t)bx * 256;
  char* ldsb = (char*)lds;

  // ---- staging: slot s holds (r=s>>2, c=(s&3)^((r>>1)&3)) ----
  const int s0 = wid*64 + lane, s1 = s0 + 512;
  const int rS0 = s0 >> 2, cS0 = (s0 & 3) ^ ((rS0 >> 1) & 3);
  const int rS1 = s1 >> 2, cS1 = (s1 & 3) ^ ((rS1 >> 1) & 3);
  const unsigned short* gA0 = A + (arow0 + rS0) * K + cS0*8;
  const unsigned short* gA1 = A + (arow0 + rS1) * K + cS1*8;
  const unsigned short* gB0 = B + (bcol0 + rS0) * K + cS0*8;
  const unsigned short* gB1 = B + (bcol0 + rS1) * K + cS1*8;
  const int ldsw0 = wid * 1024;          // round-0 uniform base (bytes)
  const int ldsw1 = 8192 + wid * 1024;   // round-1

#define STAGE_A(tt) { const int q_ = (tt)&3, k_ = (tt)*32;                 \
    GL2LDS(gA0 + k_, ldsb + q_*32768 + ldsw0);                             \
    GL2LDS(gA1 + k_, ldsb + q_*32768 + ldsw1); }
#define STAGE_B(tt) { const int q_ = (tt)&3, k_ = (tt)*32;                 \
    GL2LDS(gB0 + k_, ldsb + q_*32768 + 16384 + ldsw0);                     \
    GL2LDS(gB1 + k_, ldsb + q_*32768 + 16384 + ldsw1); }

  // ---- fragment read offset (bytes, within A or B region of a ring) ----
  const int lo16 = ((lane & 15) * 4 + ((lane >> 4) ^ ((lane >> 1) & 3))) * 16;

  f32x4 acc[8][4] = {};
  bf16x8 a0[4], a1[4], bfr[4];

  // prologue: stage tiles 0,1,2; wait tile 0 (8 loads of tiles 1,2 in flight)
  STAGE_A(0); STAGE_B(0);
  STAGE_A(1); STAGE_B(1);
  STAGE_A(2); STAGE_B(2);
  waitv8();
  __builtin_amdgcn_s_barrier();

  for (int t = 0; t < NTILE; ++t) {
    const char* bA = ldsb + (t & 3) * 32768;
    const char* bB = bA + 16384;
    // Issue ALL reads for this tile + both stages up front; the compiler's
    // partial lgkmcnt lets the first MFMA block start while a1 reads and the
    // stage issues are still in flight. MFMA-idle window = a0/bfr latency only.
#pragma unroll
    for (int mi = 0; mi < 4; ++mi)
      a0[mi] = *reinterpret_cast<const bf16x8*>(bA + wm*8192 + mi*1024 + lo16);
#pragma unroll
    for (int ni = 0; ni < 4; ++ni)
      bfr[ni] = *reinterpret_cast<const bf16x8*>(bB + wn*4096 + ni*1024 + lo16);
    if (t < NTILE - 3) STAGE_A(t + 3);
#pragma unroll
    for (int mi = 0; mi < 4; ++mi)
      a1[mi] = *reinterpret_cast<const bf16x8*>(bA + wm*8192 + (mi+4)*1024 + lo16);
    if (t < NTILE - 3) STAGE_B(t + 3);
    __builtin_amdgcn_s_setprio(1);
#pragma unroll
    for (int mi = 0; mi < 4; ++mi)
#pragma unroll
      for (int ni = 0; ni < 4; ++ni)
        acc[mi][ni] = __builtin_amdgcn_mfma_f32_16x16x32_bf16(a0[mi], bfr[ni], acc[mi][ni], 0, 0, 0);
#pragma unroll
    for (int mi = 0; mi < 4; ++mi)
#pragma unroll
      for (int ni = 0; ni < 4; ++ni)
        acc[mi+4][ni] = __builtin_amdgcn_mfma_f32_16x16x32_bf16(a1[mi], bfr[ni], acc[mi+4][ni], 0, 0, 0);
    __builtin_amdgcn_s_setprio(0);
    // ---- boundary: counted wait -> tile t+1 resident; single barrier ----
    if (t < NTILE - 3)       waitv8();
    else if (t == NTILE - 3) waitv4();
    else if (t == NTILE - 2) waitv0();
    __builtin_amdgcn_s_barrier();
  }
#undef STAGE_A
#undef STAGE_B

  // epilogue: C/D layout col=lane&15, row=(lane>>4)*4+reg
#pragma unroll
  for (int mi = 0; mi < 8; ++mi)
#pragma unroll
    for (int ni = 0; ni < 4; ++ni) {
      const size_t col = bcol0 + wn*64 + ni*16 + (lane & 15);
#pragma unroll
      for (int r = 0; r < 4; ++r) {
        const size_t row = arow0 + wm*128 + mi*16 + (lane >> 4)*4 + r;
        C[row * 2048 + col] = f2bf(acc[mi][ni][r]);
      }
    }
}

// ---------- pred GEMM (swizzled LDS): f32 out to d_out(+1) + loss partials ----
__global__ __launch_bounds__(256) void gemm_nt_pred(
    const unsigned short* __restrict__ A, const unsigned short* __restrict__ B,
    float* __restrict__ outp /* = out+1 */, const float* __restrict__ x_start,
    float* __restrict__ lpart, int b0)
{
  constexpr int K = ND;
  __shared__ unsigned short As[128*32];
  __shared__ unsigned short Bs[128*32];
  __shared__ float r2[4];
  const int tid = threadIdx.x;
  const int lane = tid & 63, wid = tid >> 6;
  const int wm = wid >> 1, wn = wid & 1;
  const size_t arow0 = (size_t)blockIdx.y * 128;
  const size_t bcol0 = (size_t)blockIdx.x * 128;
  f32x4 acc[4][4] = {};
  const int row0 = tid >> 2, row1 = row0 + 64;
  const int kc = (((tid & 3) ^ ((tid >> 3) & 3))) * 8;
  const unsigned short* ga0 = A + (arow0 + row0) * K + kc;
  const unsigned short* ga1 = A + (arow0 + row1) * K + kc;
  const unsigned short* gb0 = B + (bcol0 + row0) * K + kc;
  const unsigned short* gb1 = B + (bcol0 + row1) * K + kc;
  char* lAs = (char*)As; char* lBs = (char*)Bs;
  const int lo0 = wid * 1024, lo1 = 4096 + wid * 1024;
  const int ar = (lane & 15);
  const int ko = ((lane >> 4) ^ ((lane >> 1) & 3)) * 8;
  for (int k0 = 0; k0 < K; k0 += 32) {
    GL2LDS(ga0 + k0, lAs + lo0);
    GL2LDS(ga1 + k0, lAs + lo1);
    GL2LDS(gb0 + k0, lBs + lo0);
    GL2LDS(gb1 + k0, lBs + lo1);
    __syncthreads();
    bf16x8 af[4], bfr[4];
#pragma unroll
    for (int mi = 0; mi < 4; ++mi)
      af[mi] = *reinterpret_cast<const bf16x8*>(&As[(wm*64 + mi*16 + ar)*32 + ko]);
#pragma unroll
    for (int ni = 0; ni < 4; ++ni)
      bfr[ni] = *reinterpret_cast<const bf16x8*>(&Bs[(wn*64 + ni*16 + ar)*32 + ko]);
#pragma unroll
    for (int mi = 0; mi < 4; ++mi)
#pragma unroll
      for (int ni = 0; ni < 4; ++ni)
        acc[mi][ni] = __builtin_amdgcn_mfma_f32_16x16x32_bf16(af[mi], bfr[ni], acc[mi][ni], 0, 0, 0);
    __syncthreads();
  }
  float sse = 0.f;
#pragma unroll
  for (int mi = 0; mi < 4; ++mi)
#pragma unroll
    for (int ni = 0; ni < 4; ++ni) {
      const size_t col = bcol0 + wn*64 + ni*16 + (lane & 15);
#pragma unroll
      for (int r = 0; r < 4; ++r) {
        const size_t row = arow0 + wm*64 + mi*16 + (lane >> 4)*4 + r;  // chunk-local b
        const size_t gb  = (size_t)b0 + row;                           // global b
        const float p = acc[mi][ni][r];
        outp[gb * ND + col] = p;
        const float d = p - x_start[gb * ND + col];
        sse += d * d;
      }
    }
#pragma unroll
  for (int o = 32; o > 0; o >>= 1) sse += __shfl_xor(sse, o);
  if (lane == 0) r2[wid] = sse;
  __syncthreads();
  if (tid == 0) {
    const int slot = ((b0 >> 7) + (int)blockIdx.y) * 16 + (int)blockIdx.x;
    lpart[slot] = r2[0] + r2[1] + r2[2] + r2[3];
  }
}

// ---------- per-group: logits from F,H -> softmax -> u = sum_j c_j f_j --------
__global__ __launch_bounds__(256) void attn_u(
    const unsigned short* __restrict__ F, const unsigned short* __restrict__ H,
    const float* __restrict__ maskf, unsigned short* __restrict__ U)
{
  const int cb = blockIdx.x, tid = threadIdx.x;
  const int e0 = tid * 8, lane = tid & 63, wid = tid >> 6;
  __shared__ float red[64];
  float f[4][8], h[4][8];
#pragma unroll
  for (int i = 0; i < 4; ++i) {
    unpack8(*reinterpret_cast<const uint4*>(F + ((size_t)cb*4 + i)*ND + e0), f[i]);
    unpack8(*reinterpret_cast<const uint4*>(H + ((size_t)cb*4 + i)*ND + e0), h[i]);
  }
  float part[16];
#pragma unroll
  for (int i = 0; i < 4; ++i)
#pragma unroll
    for (int j = 0; j < 4; ++j) {
      float p = 0.f;
#pragma unroll
      for (int r = 0; r < 8; ++r) p += f[i][r] * h[j][r];
      part[i*4+j] = p;
    }
#pragma unroll
  for (int idx = 0; idx < 16; ++idx)
#pragma unroll
    for (int o = 32; o > 0; o >>= 1) part[idx] += __shfl_xor(part[idx], o);
  if (lane == 0) {
#pragma unroll
    for (int idx = 0; idx < 16; ++idx) red[wid*16 + idx] = part[idx];
  }
  __syncthreads();
  float lg[16];
#pragma unroll
  for (int idx = 0; idx < 16; ++idx)
    lg[idx] = red[idx] + red[16+idx] + red[32+idx] + red[48+idx];

  const float scale = 0.022097086912079608f;  // 2048^-0.5
  float m[4];
#pragma unroll
  for (int j = 0; j < 4; ++j) m[j] = maskf[(size_t)cb*NT + j];
  const float denom = fmaxf(m[0]+m[1]+m[2]+m[3], 1.0f);
  float c[4] = {0.f, 0.f, 0.f, 0.f};
#pragma unroll
  for (int i = 0; i < 4; ++i) {
    float x[4];
#pragma unroll
    for (int j = 0; j < 4; ++j) x[j] = (m[j] > 0.f) ? lg[i*4+j]*scale : -1e9f;
    const float mx = fmaxf(fmaxf(x[0],x[1]), fmaxf(x[2],x[3]));
    float p[4], sum = 0.f;
#pragma unroll
    for (int j = 0; j < 4; ++j) { p[j] = expf(x[j]-mx); sum += p[j]; }
    const float w = m[i] / (sum * denom);
#pragma unroll
    for (int j = 0; j < 4; ++j) c[j] += p[j] * w;
  }
  unsigned int pk[4];
#pragma unroll
  for (int jj = 0; jj < 4; ++jj) {
    float ulo = c[0]*f[0][2*jj]   + c[1]*f[1][2*jj]   + c[2]*f[2][2*jj]   + c[3]*f[3][2*jj];
    float uhi = c[0]*f[0][2*jj+1] + c[1]*f[1][2*jj+1] + c[2]*f[2][2*jj+1] + c[3]*f[3][2*jj+1];
    pk[jj] = (unsigned int)f2bf(ulo) | ((unsigned int)f2bf(uhi) << 16);
  }
  *reinterpret_cast<uint4*>(U + (size_t)cb*ND + e0) = make_uint4(pk[0],pk[1],pk[2],pk[3]);
}

// ---------- deterministic loss reduce (1024 fixed slots) ----------------------
__global__ __launch_bounds__(256) void loss_final(const float* __restrict__ lpart,
                                                  float* __restrict__ out) {
  const int tid = threadIdx.x;
  float s = 0.f;
  for (int i = tid; i < 1024; i += 256) s += lpart[i];
#pragma unroll
  for (int o = 32; o > 0; o >>= 1) s += __shfl_xor(s, o);
  __shared__ float red[4];
  const int lane = tid & 63, wid = tid >> 6;
  if (lane == 0) red[wid] = s;
  __syncthreads();
  if (tid == 0) out[0] = (red[0]+red[1]+red[2]+red[3]) * (1.0f / 16777216.0f);
}

extern "C" void kernel_launch(void* const* d_in, const int* in_sizes, int n_in,
                              void* d_out, int out_size, void* d_ws, size_t ws_size,
                              hipStream_t stream) {
  const float* x_start   = (const float*)d_in[0];
  const int*   tarr      = (const int*)  d_in[1];
  const float* noise     = (const float*)d_in[2];
  const float* cond_src  = (const float*)d_in[3];
  const float* cond_tgt  = (const float*)d_in[4];
  const float* w_q       = (const float*)d_in[5];
  const float* w_k       = (const float*)d_in[6];
  const float* w_v       = (const float*)d_in[7];
  const float* sqrt_ac   = (const float*)d_in[8];
  const float* sqrt_omac = (const float*)d_in[9];
  float* out = (float*)d_out;
  char*  ws  = (char*)d_ws;

  // adaptive chunk size: need(cb) = 16 MiB (G+Wv) + cb*36880 (F+H+U+mask) + 4 KiB
  size_t CB;
  if      (ws_size >= 318902272ull) CB = 8192;
  else if (ws_size >= 167841792ull) CB = 4096;
  else if (ws_size >=  92311552ull) CB = 2048;
  else if (ws_size >=  54546432ull) CB = 1024;
  else return;  // < 52 MiB workspace: cannot run

  const size_t offG  = 0;
  const size_t offWv = 8388608;
  const size_t offF  = 16777216;
  const size_t szF   = CB * 16384;            // 4*CB*2048*2 bytes
  const size_t offH  = offF + szF;
  const size_t offU  = offH + szF;
  const size_t offMask = offU + CB * 4096;
  const size_t offLp   = offMask + CB * 16;

  unsigned short* G    = (unsigned short*)(ws + offG);
  unsigned short* WvBf = (unsigned short*)(ws + offWv);
  unsigned short* F    = (unsigned short*)(ws + offF);
  unsigned short* H    = (unsigned short*)(ws + offH);
  unsigned short* U    = (unsigned short*)(ws + offU);
  float* maskC = (float*)(ws + offMask);
  float* lpart = (float*)(ws + offLp);
  // setup-phase aliases (dead before chunk 0 writes F/H)
  unsigned short* WqT = F;
  unsigned short* WkT = H;

  transpose_cast<<<dim3(32, 32), 256, 0, stream>>>(w_q, WqT);
  transpose_cast<<<dim3(32, 32), 256, 0, stream>>>(w_k, WkT);
  cast_w<<<dim3(4096), 256, 0, stream>>>(w_v, WvBf);
  gemm_nt_bf16<<<dim3(16, 16), 256, 0, stream>>>(WqT, WkT, G);   // G = Wq^T Wk

  const int nchunks = NB / (int)CB;
  for (int ci = 0; ci < nchunks; ++ci) {
    const int b0 = ci * (int)CB;
    prep_tokens<<<dim3(NT, (int)CB), 256, 0, stream>>>(
        x_start, tarr, noise, cond_src, cond_tgt, sqrt_ac, sqrt_omac, F, maskC, b0);
    gemm_nt_256<<<dim3(ND/256, (NT*(int)CB)/256), 512, 0, stream>>>(F, G, H);  // H = F G^T
    attn_u<<<dim3((int)CB), 256, 0, stream>>>(F, H, maskC, U);
    gemm_nt_pred<<<dim3(16, (int)CB / 128), 256, 0, stream>>>(
        U, WvBf, out + 1, x_start, lpart, b0);                          // pred = U Wv^T
  }
  loss_final<<<dim3(1), 256, 0, stream>>>(lpart, out);
}

// Round 6
// 581.174 us; speedup vs baseline: 1.1660x; 1.0212x over previous
//
#include <hip/hip_runtime.h>
#include <math.h>

#define NB 8192
#define ND 2048
#define NT 4

using bf16x8 = __attribute__((ext_vector_type(8))) short;
using f32x4  = __attribute__((ext_vector_type(4))) float;

__device__ inline unsigned short f2bf(float f) {
  unsigned int u = __float_as_uint(f);
  u += 0x7FFFu + ((u >> 16) & 1u);           // RNE
  return (unsigned short)(u >> 16);
}
__device__ inline void unpack8(uint4 u, float* f) {
  f[0] = __uint_as_float(u.x << 16); f[1] = __uint_as_float(u.x & 0xFFFF0000u);
  f[2] = __uint_as_float(u.y << 16); f[3] = __uint_as_float(u.y & 0xFFFF0000u);
  f[4] = __uint_as_float(u.z << 16); f[5] = __uint_as_float(u.z & 0xFFFF0000u);
  f[6] = __uint_as_float(u.w << 16); f[7] = __uint_as_float(u.w & 0xFFFF0000u);
}

#define GL2LDS(g, l) __builtin_amdgcn_global_load_lds( \
    (const __attribute__((address_space(1))) void*)(g), \
    (__attribute__((address_space(3))) void*)(l), 16, 0, 0)

__device__ inline void waitv0() { asm volatile("s_waitcnt vmcnt(0)" ::: "memory"); }

// LDS bijection (per 16-row x 32-k bf16 half-subtile, 16B chunks):
//   (row r, k-chunk c) stored at slot r*4 + (c ^ ((r>>1)&3))
// Any 8 consecutive lanes of a ds_read_b128 hit all 8 slot%8 groups exactly
// once -> conflict-free (verified: SQ_LDS_BANK_CONFLICT==0 in r4/r5).
// Writes via global_load_lds stay linear; permutation applied to the GLOBAL
// source address (m173 pattern).

// ---------- transpose+cast: WT[d][e] = (bf16)W[e][d], 2048x2048 ---------------
__global__ __launch_bounds__(256) void transpose_cast(
    const float* __restrict__ W, unsigned short* __restrict__ WT)
{
  __shared__ float tile[64][65];
  const int t = threadIdx.x, r = t >> 2, c0 = (t & 3) * 16;
  const int bx = blockIdx.x * 64, by = blockIdx.y * 64;
  const float* src = W + (size_t)(by + r) * ND + bx + c0;
#pragma unroll
  for (int j = 0; j < 4; ++j) {
    float4 v = *reinterpret_cast<const float4*>(src + j * 4);
    tile[r][c0 + j*4 + 0] = v.x; tile[r][c0 + j*4 + 1] = v.y;
    tile[r][c0 + j*4 + 2] = v.z; tile[r][c0 + j*4 + 3] = v.w;
  }
  __syncthreads();
  unsigned int pk[8];
#pragma unroll
  for (int j = 0; j < 8; ++j) {
    unsigned int lo = f2bf(tile[c0 + 2*j    ][r]);
    unsigned int hi = f2bf(tile[c0 + 2*j + 1][r]);
    pk[j] = lo | (hi << 16);
  }
  unsigned short* dst = WT + (size_t)(bx + r) * ND + by + c0;
  *reinterpret_cast<uint4*>(dst)     = make_uint4(pk[0], pk[1], pk[2], pk[3]);
  *reinterpret_cast<uint4*>(dst + 8) = make_uint4(pk[4], pk[5], pk[6], pk[7]);
}

// ---------- plain cast f32 -> bf16 (row-major copy) ---------------------------
__global__ __launch_bounds__(256) void cast_w(const float* __restrict__ w,
                                              unsigned short* __restrict__ o) {
  const size_t i4 = ((size_t)blockIdx.x * 256 + threadIdx.x) * 4;
  float4 f = *reinterpret_cast<const float4*>(w + i4);
  ushort4 r;
  r.x = f2bf(f.x); r.y = f2bf(f.y); r.z = f2bf(f.z); r.w = f2bf(f.w);
  *reinterpret_cast<ushort4*>(o + i4) = r;
}

// ---------- tokens + mask + LayerNorm -> F chunk (bf16) -----------------------
__global__ __launch_bounds__(256) void prep_tokens(
    const float* __restrict__ x_start, const int* __restrict__ tarr,
    const float* __restrict__ noise, const float* __restrict__ cond_src,
    const float* __restrict__ cond_tgt, const float* __restrict__ sqrt_ac,
    const float* __restrict__ sqrt_omac, unsigned short* __restrict__ F,
    float* __restrict__ maskf, int b0)
{
  const int cb = blockIdx.y, tok = blockIdx.x, tid = threadIdx.x;
  const int b = b0 + cb;
  const int e0 = tid * 8;
  float v[8];
  if (tok == 0) {
    const int tb = tarr[b];
    const float sa = sqrt_ac[tb], so = sqrt_omac[tb];
    const float4* xs = reinterpret_cast<const float4*>(x_start + (size_t)b * ND + e0);
    const float4* ns = reinterpret_cast<const float4*>(noise + (size_t)b * ND + e0);
    float4 x0 = xs[0], x1 = xs[1], n0 = ns[0], n1 = ns[1];
    v[0] = sa*x0.x + so*n0.x; v[1] = sa*x0.y + so*n0.y;
    v[2] = sa*x0.z + so*n0.z; v[3] = sa*x0.w + so*n0.w;
    v[4] = sa*x1.x + so*n1.x; v[5] = sa*x1.y + so*n1.y;
    v[6] = sa*x1.z + so*n1.z; v[7] = sa*x1.w + so*n1.w;
  } else if (tok == 1) {
    const float tf = (float)tarr[b];
    const float cc = -9.210340371976184f / 1023.0f;  // -ln(10000)/(half-1)
#pragma unroll
    for (int j = 0; j < 8; ++j) {
      int e = e0 + j;
      int i = (e < 1024) ? e : (e - 1024);
      float a = tf * expf((float)i * cc);
      v[j] = (e < 1024) ? sinf(a) : cosf(a);
    }
  } else {
    const float* src = (tok == 2) ? cond_src : cond_tgt;
    const float4* ps = reinterpret_cast<const float4*>(src + (size_t)b * ND + e0);
    float4 a0 = ps[0], a1 = ps[1];
    v[0]=a0.x; v[1]=a0.y; v[2]=a0.z; v[3]=a0.w;
    v[4]=a1.x; v[5]=a1.y; v[6]=a1.z; v[7]=a1.w;
  }
  float s = 0.f, s2 = 0.f, sab = 0.f;
#pragma unroll
  for (int j = 0; j < 8; ++j) { s += v[j]; s2 += v[j]*v[j]; sab += fabsf(v[j]); }
#pragma unroll
  for (int o = 32; o > 0; o >>= 1) {
    s += __shfl_xor(s, o); s2 += __shfl_xor(s2, o); sab += __shfl_xor(sab, o);
  }
  __shared__ float red[12];
  const int lane = tid & 63, wid = tid >> 6;
  if (lane == 0) { red[wid*3+0] = s; red[wid*3+1] = s2; red[wid*3+2] = sab; }
  __syncthreads();
  s   = red[0] + red[3] + red[6] + red[9];
  s2  = red[1] + red[4] + red[7] + red[10];
  sab = red[2] + red[5] + red[8] + red[11];
  const float mu  = s * (1.0f / ND);
  const float var = s2 * (1.0f / ND) - mu * mu;
  const float rs  = rsqrtf(var + 1e-5f);
  if (tid == 0) maskf[(size_t)cb*NT + tok] = (sab > 0.0f) ? 1.0f : 0.0f;
  unsigned int pk[4];
#pragma unroll
  for (int j = 0; j < 4; ++j) {
    unsigned int lo = f2bf((v[2*j]   - mu) * rs);
    unsigned int hi = f2bf((v[2*j+1] - mu) * rs);
    pk[j] = lo | (hi << 16);
  }
  *reinterpret_cast<uint4*>(F + ((size_t)cb*NT + tok) * ND + e0) =
      make_uint4(pk[0], pk[1], pk[2], pk[3]);
}

// ---------- 128^2 GEMM core (swizzled LDS): C=A*B^T, bf16 out -----------------
__global__ __launch_bounds__(256) void gemm_nt_bf16(
    const unsigned short* __restrict__ A, const unsigned short* __restrict__ B,
    unsigned short* __restrict__ C)
{
  constexpr int K = ND;
  __shared__ unsigned short As[128*32];
  __shared__ unsigned short Bs[128*32];
  const int tid = threadIdx.x;
  const int lane = tid & 63, wid = tid >> 6;
  const int wm = wid >> 1, wn = wid & 1;
  const size_t arow0 = (size_t)blockIdx.y * 128;
  const size_t bcol0 = (size_t)blockIdx.x * 128;
  f32x4 acc[4][4] = {};
  const int row0 = tid >> 2, row1 = row0 + 64;
  const int kc = (((tid & 3) ^ ((tid >> 3) & 3))) * 8;   // swizzled source chunk
  const unsigned short* ga0 = A + (arow0 + row0) * K + kc;
  const unsigned short* ga1 = A + (arow0 + row1) * K + kc;
  const unsigned short* gb0 = B + (bcol0 + row0) * K + kc;
  const unsigned short* gb1 = B + (bcol0 + row1) * K + kc;
  char* lAs = (char*)As; char* lBs = (char*)Bs;
  const int lo0 = wid * 1024, lo1 = 4096 + wid * 1024;
  const int ar = (lane & 15);
  const int ko = ((lane >> 4) ^ ((lane >> 1) & 3)) * 8;  // swizzled read chunk
  for (int k0 = 0; k0 < K; k0 += 32) {
    GL2LDS(ga0 + k0, lAs + lo0);
    GL2LDS(ga1 + k0, lAs + lo1);
    GL2LDS(gb0 + k0, lBs + lo0);
    GL2LDS(gb1 + k0, lBs + lo1);
    __syncthreads();
    bf16x8 af[4], bfr[4];
#pragma unroll
    for (int mi = 0; mi < 4; ++mi)
      af[mi] = *reinterpret_cast<const bf16x8*>(&As[(wm*64 + mi*16 + ar)*32 + ko]);
#pragma unroll
    for (int ni = 0; ni < 4; ++ni)
      bfr[ni] = *reinterpret_cast<const bf16x8*>(&Bs[(wn*64 + ni*16 + ar)*32 + ko]);
#pragma unroll
    for (int mi = 0; mi < 4; ++mi)
#pragma unroll
      for (int ni = 0; ni < 4; ++ni)
        acc[mi][ni] = __builtin_amdgcn_mfma_f32_16x16x32_bf16(af[mi], bfr[ni], acc[mi][ni], 0, 0, 0);
    __syncthreads();
  }
#pragma unroll
  for (int mi = 0; mi < 4; ++mi)
#pragma unroll
    for (int ni = 0; ni < 4; ++ni) {
      const size_t col = bcol0 + wn*64 + ni*16 + (lane & 15);
#pragma unroll
      for (int r = 0; r < 4; ++r) {
        const size_t row = arow0 + wm*64 + mi*16 + (lane >> 4)*4 + r;
        C[row * ND + col] = f2bf(acc[mi][ni][r]);
      }
    }
}

// ---------- 256^2 tile, BK=64, ring-2 LDS, 1 barrier/tile, covered vmcnt(0) ---
// Ring q (q=t&1) at q*65536 bytes: A half0 @+0, A half1 @+16384,
//                                  B half0 @+32768, B half1 @+49152.
// Stage of tile t+1 targets ring (t+1)&1 = opposite ring -> no intra-iteration
// read/write conflict -> single barrier per tile. The boundary vmcnt(0) waits
// only on t+1's 8 loads issued a full tile (~2500 cy) earlier -> latency
// covered, drain is free (unlike the m97 pre-barrier drain).
__global__ __launch_bounds__(512, 2) void gemm_nt_256(
    const unsigned short* __restrict__ A, const unsigned short* __restrict__ B,
    unsigned short* __restrict__ C)
{
  constexpr int K = 2048;
  constexpr int NTILE = K / 64;  // 32
  __shared__ unsigned short lds[65536];  // 128 KiB: 2 rings x (A 32K + B 32K)
  const int tid = threadIdx.x;
  const int lane = tid & 63, wid = tid >> 6;
  const int wm = wid >> 2, wn = wid & 3;

  // XCD-aware swizzle (nwg%8==0 always: nwg = 8*(M/256))
  const int GX = (int)gridDim.x;
  const int nwg = GX * (int)gridDim.y;
  const int o = (int)blockIdx.y * GX + (int)blockIdx.x;
  const int swz = (o & 7) * (nwg >> 3) + (o >> 3);
  const int bx = swz % GX, by = swz / GX;

  const size_t arow0 = (size_t)by * 256;
  const size_t bcol0 = (size_t)bx * 256;
  char* ldsb = (char*)lds;

  // ---- staging: per 32-k half, slot s holds (r=s>>2, c=(s&3)^((r>>1)&3)) ----
  const int s0 = wid*64 + lane, s1 = s0 + 512;
  const int rS0 = s0 >> 2, cS0 = (s0 & 3) ^ ((rS0 >> 1) & 3);
  const int rS1 = s1 >> 2, cS1 = (s1 & 3) ^ ((rS1 >> 1) & 3);
  const unsigned short* gA0 = A + (arow0 + rS0) * K + cS0*8;
  const unsigned short* gA1 = A + (arow0 + rS1) * K + cS1*8;
  const unsigned short* gB0 = B + (bcol0 + rS0) * K + cS0*8;
  const unsigned short* gB1 = B + (bcol0 + rS1) * K + cS1*8;
  const int ldsw0 = wid * 1024;          // slot-group base within a 16K half
  const int ldsw1 = 8192 + wid * 1024;

#define STAGE_A(tt) { const int q_ = ((tt)&1)*65536; const int k_ = (tt)*64;   \
    GL2LDS(gA0 + k_,      ldsb + q_ + ldsw0);                                  \
    GL2LDS(gA1 + k_,      ldsb + q_ + ldsw1);                                  \
    GL2LDS(gA0 + k_ + 32, ldsb + q_ + 16384 + ldsw0);                          \
    GL2LDS(gA1 + k_ + 32, ldsb + q_ + 16384 + ldsw1); }
#define STAGE_B(tt) { const int q_ = ((tt)&1)*65536; const int k_ = (tt)*64;   \
    GL2LDS(gB0 + k_,      ldsb + q_ + 32768 + ldsw0);                          \
    GL2LDS(gB1 + k_,      ldsb + q_ + 32768 + ldsw1);                          \
    GL2LDS(gB0 + k_ + 32, ldsb + q_ + 49152 + ldsw0);                          \
    GL2LDS(gB1 + k_ + 32, ldsb + q_ + 49152 + ldsw1); }

  // ---- fragment read offset (bytes, within a 16K half region) ----
  const int lo16 = ((lane & 15) * 4 + ((lane >> 4) ^ ((lane >> 1) & 3))) * 16;

  f32x4 acc[8][4] = {};
  bf16x8 af[8], bfr[4];

  // prologue: stage tile 0 into ring 0; drain; barrier
  STAGE_A(0); STAGE_B(0);
  waitv0();
  __builtin_amdgcn_s_barrier();

  for (int t = 0; t < NTILE; ++t) {
    const char* rg = ldsb + (t & 1) * 65536;
    // ---- k-half 0: 8 A-frags + 4 B-frags; stage A of t+1 (other ring) ----
#pragma unroll
    for (int mi = 0; mi < 8; ++mi)
      af[mi] = *reinterpret_cast<const bf16x8*>(rg + wm*8192 + mi*1024 + lo16);
#pragma unroll
    for (int ni = 0; ni < 4; ++ni)
      bfr[ni] = *reinterpret_cast<const bf16x8*>(rg + 32768 + wn*4096 + ni*1024 + lo16);
    if (t + 1 < NTILE) STAGE_A(t + 1);
    __builtin_amdgcn_s_setprio(1);
#pragma unroll
    for (int mi = 0; mi < 8; ++mi)
#pragma unroll
      for (int ni = 0; ni < 4; ++ni)
        acc[mi][ni] = __builtin_amdgcn_mfma_f32_16x16x32_bf16(af[mi], bfr[ni], acc[mi][ni], 0, 0, 0);
    __builtin_amdgcn_s_setprio(0);
    // ---- k-half 1 ----
#pragma unroll
    for (int mi = 0; mi < 8; ++mi)
      af[mi] = *reinterpret_cast<const bf16x8*>(rg + 16384 + wm*8192 + mi*1024 + lo16);
#pragma unroll
    for (int ni = 0; ni < 4; ++ni)
      bfr[ni] = *reinterpret_cast<const bf16x8*>(rg + 49152 + wn*4096 + ni*1024 + lo16);
    if (t + 1 < NTILE) STAGE_B(t + 1);
    __builtin_amdgcn_s_setprio(1);
#pragma unroll
    for (int mi = 0; mi < 8; ++mi)
#pragma unroll
      for (int ni = 0; ni < 4; ++ni)
        acc[mi][ni] = __builtin_amdgcn_mfma_f32_16x16x32_bf16(af[mi], bfr[ni], acc[mi][ni], 0, 0, 0);
    __builtin_amdgcn_s_setprio(0);
    // ---- boundary: t+1's 8 loads (issued ~1 tile ago) -> resident; sync ----
    waitv0();
    __builtin_amdgcn_s_barrier();
  }
#undef STAGE_A
#undef STAGE_B

  // epilogue: C/D layout col=lane&15, row=(lane>>4)*4+reg
#pragma unroll
  for (int mi = 0; mi < 8; ++mi)
#pragma unroll
    for (int ni = 0; ni < 4; ++ni) {
      const size_t col = bcol0 + wn*64 + ni*16 + (lane & 15);
#pragma unroll
      for (int r = 0; r < 4; ++r) {
        const size_t row = arow0 + wm*128 + mi*16 + (lane >> 4)*4 + r;
        C[row * 2048 + col] = f2bf(acc[mi][ni][r]);
      }
    }
}

// ---------- pred GEMM (swizzled LDS): f32 out to d_out(+1) + loss partials ----
__global__ __launch_bounds__(256) void gemm_nt_pred(
    const unsigned short* __restrict__ A, const unsigned short* __restrict__ B,
    float* __restrict__ outp /* = out+1 */, const float* __restrict__ x_start,
    float* __restrict__ lpart, int b0)
{
  constexpr int K = ND;
  __shared__ unsigned short As[128*32];
  __shared__ unsigned short Bs[128*32];
  __shared__ float r2[4];
  const int tid = threadIdx.x;
  const int lane = tid & 63, wid = tid >> 6;
  const int wm = wid >> 1, wn = wid & 1;
  const size_t arow0 = (size_t)blockIdx.y * 128;
  const size_t bcol0 = (size_t)blockIdx.x * 128;
  f32x4 acc[4][4] = {};
  const int row0 = tid >> 2, row1 = row0 + 64;
  const int kc = (((tid & 3) ^ ((tid >> 3) & 3))) * 8;
  const unsigned short* ga0 = A + (arow0 + row0) * K + kc;
  const unsigned short* ga1 = A + (arow0 + row1) * K + kc;
  const unsigned short* gb0 = B + (bcol0 + row0) * K + kc;
  const unsigned short* gb1 = B + (bcol0 + row1) * K + kc;
  char* lAs = (char*)As; char* lBs = (char*)Bs;
  const int lo0 = wid * 1024, lo1 = 4096 + wid * 1024;
  const int ar = (lane & 15);
  const int ko = ((lane >> 4) ^ ((lane >> 1) & 3)) * 8;
  for (int k0 = 0; k0 < K; k0 += 32) {
    GL2LDS(ga0 + k0, lAs + lo0);
    GL2LDS(ga1 + k0, lAs + lo1);
    GL2LDS(gb0 + k0, lBs + lo0);
    GL2LDS(gb1 + k0, lBs + lo1);
    __syncthreads();
    bf16x8 af[4], bfr[4];
#pragma unroll
    for (int mi = 0; mi < 4; ++mi)
      af[mi] = *reinterpret_cast<const bf16x8*>(&As[(wm*64 + mi*16 + ar)*32 + ko]);
#pragma unroll
    for (int ni = 0; ni < 4; ++ni)
      bfr[ni] = *reinterpret_cast<const bf16x8*>(&Bs[(wn*64 + ni*16 + ar)*32 + ko]);
#pragma unroll
    for (int mi = 0; mi < 4; ++mi)
#pragma unroll
      for (int ni = 0; ni < 4; ++ni)
        acc[mi][ni] = __builtin_amdgcn_mfma_f32_16x16x32_bf16(af[mi], bfr[ni], acc[mi][ni], 0, 0, 0);
    __syncthreads();
  }
  float sse = 0.f;
#pragma unroll
  for (int mi = 0; mi < 4; ++mi)
#pragma unroll
    for (int ni = 0; ni < 4; ++ni) {
      const size_t col = bcol0 + wn*64 + ni*16 + (lane & 15);
#pragma unroll
      for (int r = 0; r < 4; ++r) {
        const size_t row = arow0 + wm*64 + mi*16 + (lane >> 4)*4 + r;  // chunk-local b
        const size_t gb  = (size_t)b0 + row;                           // global b
        const float p = acc[mi][ni][r];
        outp[gb * ND + col] = p;
        const float d = p - x_start[gb * ND + col];
        sse += d * d;
      }
    }
#pragma unroll
  for (int o = 32; o > 0; o >>= 1) sse += __shfl_xor(sse, o);
  if (lane == 0) r2[wid] = sse;
  __syncthreads();
  if (tid == 0) {
    const int slot = ((b0 >> 7) + (int)blockIdx.y) * 16 + (int)blockIdx.x;
    lpart[slot] = r2[0] + r2[1] + r2[2] + r2[3];
  }
}

// ---------- per-group: logits from F,H -> softmax -> u = sum_j c_j f_j --------
__global__ __launch_bounds__(256) void attn_u(
    const unsigned short* __restrict__ F, const unsigned short* __restrict__ H,
    const float* __restrict__ maskf, unsigned short* __restrict__ U)
{
  const int cb = blockIdx.x, tid = threadIdx.x;
  const int e0 = tid * 8, lane = tid & 63, wid = tid >> 6;
  __shared__ float red[64];
  float f[4][8], h[4][8];
#pragma unroll
  for (int i = 0; i < 4; ++i) {
    unpack8(*reinterpret_cast<const uint4*>(F + ((size_t)cb*4 + i)*ND + e0), f[i]);
    unpack8(*reinterpret_cast<const uint4*>(H + ((size_t)cb*4 + i)*ND + e0), h[i]);
  }
  float part[16];
#pragma unroll
  for (int i = 0; i < 4; ++i)
#pragma unroll
    for (int j = 0; j < 4; ++j) {
      float p = 0.f;
#pragma unroll
      for (int r = 0; r < 8; ++r) p += f[i][r] * h[j][r];
      part[i*4+j] = p;
    }
#pragma unroll
  for (int idx = 0; idx < 16; ++idx)
#pragma unroll
    for (int o = 32; o > 0; o >>= 1) part[idx] += __shfl_xor(part[idx], o);
  if (lane == 0) {
#pragma unroll
    for (int idx = 0; idx < 16; ++idx) red[wid*16 + idx] = part[idx];
  }
  __syncthreads();
  float lg[16];
#pragma unroll
  for (int idx = 0; idx < 16; ++idx)
    lg[idx] = red[idx] + red[16+idx] + red[32+idx] + red[48+idx];

  const float scale = 0.022097086912079608f;  // 2048^-0.5
  float m[4];
#pragma unroll
  for (int j = 0; j < 4; ++j) m[j] = maskf[(size_t)cb*NT + j];
  const float denom = fmaxf(m[0]+m[1]+m[2]+m[3], 1.0f);
  float c[4] = {0.f, 0.f, 0.f, 0.f};
#pragma unroll
  for (int i = 0; i < 4; ++i) {
    float x[4];
#pragma unroll
    for (int j = 0; j < 4; ++j) x[j] = (m[j] > 0.f) ? lg[i*4+j]*scale : -1e9f;
    const float mx = fmaxf(fmaxf(x[0],x[1]), fmaxf(x[2],x[3]));
    float p[4], sum = 0.f;
#pragma unroll
    for (int j = 0; j < 4; ++j) { p[j] = expf(x[j]-mx); sum += p[j]; }
    const float w = m[i] / (sum * denom);
#pragma unroll
    for (int j = 0; j < 4; ++j) c[j] += p[j] * w;
  }
  unsigned int pk[4];
#pragma unroll
  for (int jj = 0; jj < 4; ++jj) {
    float ulo = c[0]*f[0][2*jj]   + c[1]*f[1][2*jj]   + c[2]*f[2][2*jj]   + c[3]*f[3][2*jj];
    float uhi = c[0]*f[0][2*jj+1] + c[1]*f[1][2*jj+1] + c[2]*f[2][2*jj+1] + c[3]*f[3][2*jj+1];
    pk[jj] = (unsigned int)f2bf(ulo) | ((unsigned int)f2bf(uhi) << 16);
  }
  *reinterpret_cast<uint4*>(U + (size_t)cb*ND + e0) = make_uint4(pk[0],pk[1],pk[2],pk[3]);
}

// ---------- deterministic loss reduce (1024 fixed slots) ----------------------
__global__ __launch_bounds__(256) void loss_final(const float* __restrict__ lpart,
                                                  float* __restrict__ out) {
  const int tid = threadIdx.x;
  float s = 0.f;
  for (int i = tid; i < 1024; i += 256) s += lpart[i];
#pragma unroll
  for (int o = 32; o > 0; o >>= 1) s += __shfl_xor(s, o);
  __shared__ float red[4];
  const int lane = tid & 63, wid = tid >> 6;
  if (lane == 0) red[wid] = s;
  __syncthreads();
  if (tid == 0) out[0] = (red[0]+red[1]+red[2]+red[3]) * (1.0f / 16777216.0f);
}

extern "C" void kernel_launch(void* const* d_in, const int* in_sizes, int n_in,
                              void* d_out, int out_size, void* d_ws, size_t ws_size,
                              hipStream_t stream) {
  const float* x_start   = (const float*)d_in[0];
  const int*   tarr      = (const int*)  d_in[1];
  const float* noise     = (const float*)d_in[2];
  const float* cond_src  = (const float*)d_in[3];
  const float* cond_tgt  = (const float*)d_in[4];
  const float* w_q       = (const float*)d_in[5];
  const float* w_k       = (const float*)d_in[6];
  const float* w_v       = (const float*)d_in[7];
  const float* sqrt_ac   = (const float*)d_in[8];
  const float* sqrt_omac = (const float*)d_in[9];
  float* out = (float*)d_out;
  char*  ws  = (char*)d_ws;

  // adaptive chunk size: need(cb) = 16 MiB (G+Wv) + cb*36880 (F+H+U+mask) + 4 KiB
  size_t CB;
  if      (ws_size >= 318902272ull) CB = 8192;
  else if (ws_size >= 167841792ull) CB = 4096;
  else if (ws_size >=  92311552ull) CB = 2048;
  else if (ws_size >=  54546432ull) CB = 1024;
  else return;  // < 52 MiB workspace: cannot run

  const size_t offG  = 0;
  const size_t offWv = 8388608;
  const size_t offF  = 16777216;
  const size_t szF   = CB * 16384;            // 4*CB*2048*2 bytes
  const size_t offH  = offF + szF;
  const size_t offU  = offH + szF;
  const size_t offMask = offU + CB * 4096;
  const size_t offLp   = offMask + CB * 16;

  unsigned short* G    = (unsigned short*)(ws + offG);
  unsigned short* WvBf = (unsigned short*)(ws + offWv);
  unsigned short* F    = (unsigned short*)(ws + offF);
  unsigned short* H    = (unsigned short*)(ws + offH);
  unsigned short* U    = (unsigned short*)(ws + offU);
  float* maskC = (float*)(ws + offMask);
  float* lpart = (float*)(ws + offLp);
  // setup-phase aliases (dead before chunk 0 writes F/H)
  unsigned short* WqT = F;
  unsigned short* WkT = H;

  transpose_cast<<<dim3(32, 32), 256, 0, stream>>>(w_q, WqT);
  transpose_cast<<<dim3(32, 32), 256, 0, stream>>>(w_k, WkT);
  cast_w<<<dim3(4096), 256, 0, stream>>>(w_v, WvBf);
  gemm_nt_bf16<<<dim3(16, 16), 256, 0, stream>>>(WqT, WkT, G);   // G = Wq^T Wk

  const int nchunks = NB / (int)CB;
  for (int ci = 0; ci < nchunks; ++ci) {
    const int b0 = ci * (int)CB;
    prep_tokens<<<dim3(NT, (int)CB), 256, 0, stream>>>(
        x_start, tarr, noise, cond_src, cond_tgt, sqrt_ac, sqrt_omac, F, maskC, b0);
    gemm_nt_256<<<dim3(ND/256, (NT*(int)CB)/256), 512, 0, stream>>>(F, G, H);  // H = F G^T
    attn_u<<<dim3((int)CB), 256, 0, stream>>>(F, H, maskC, U);
    gemm_nt_pred<<<dim3(16, (int)CB / 128), 256, 0, stream>>>(
        U, WvBf, out + 1, x_start, lpart, b0);                          // pred = U Wv^T
  }
  loss_final<<<dim3(1), 256, 0, stream>>>(lpart, out);
}

// Round 7
// 575.468 us; speedup vs baseline: 1.1776x; 1.0099x over previous
//
#include <hip/hip_runtime.h>
#include <math.h>

#define NB 8192
#define ND 2048
#define NT 4

using bf16x8 = __attribute__((ext_vector_type(8))) short;
using f32x4  = __attribute__((ext_vector_type(4))) float;

__device__ inline unsigned short f2bf(float f) {
  unsigned int u = __float_as_uint(f);
  u += 0x7FFFu + ((u >> 16) & 1u);           // RNE
  return (unsigned short)(u >> 16);
}
__device__ inline void unpack8(uint4 u, float* f) {
  f[0] = __uint_as_float(u.x << 16); f[1] = __uint_as_float(u.x & 0xFFFF0000u);
  f[2] = __uint_as_float(u.y << 16); f[3] = __uint_as_float(u.y & 0xFFFF0000u);
  f[4] = __uint_as_float(u.z << 16); f[5] = __uint_as_float(u.z & 0xFFFF0000u);
  f[6] = __uint_as_float(u.w << 16); f[7] = __uint_as_float(u.w & 0xFFFF0000u);
}

#define GL2LDS(g, l) __builtin_amdgcn_global_load_lds( \
    (const __attribute__((address_space(1))) void*)(g), \
    (__attribute__((address_space(3))) void*)(l), 16, 0, 0)

__device__ inline void waitv0() { asm volatile("s_waitcnt vmcnt(0)" ::: "memory"); }

// LDS bijection (per 32-k half, 16B chunks): slot s <-> (r=s>>2, c=(s&3)^((r>>1)&3))
// -> 8 consecutive lanes of a ds_read_b128 hit 8 distinct slot%8 groups:
// conflict-free (verified SQ_LDS_BANK_CONFLICT==0, r4-r6). Writes linear via
// global_load_lds; permutation applied to the GLOBAL source address (m173).

// ---------- transpose+cast: WT[d][e] = (bf16)W[e][d], 2048x2048 ---------------
__global__ __launch_bounds__(256) void transpose_cast(
    const float* __restrict__ W, unsigned short* __restrict__ WT)
{
  __shared__ float tile[64][65];
  const int t = threadIdx.x, r = t >> 2, c0 = (t & 3) * 16;
  const int bx = blockIdx.x * 64, by = blockIdx.y * 64;
  const float* src = W + (size_t)(by + r) * ND + bx + c0;
#pragma unroll
  for (int j = 0; j < 4; ++j) {
    float4 v = *reinterpret_cast<const float4*>(src + j * 4);
    tile[r][c0 + j*4 + 0] = v.x; tile[r][c0 + j*4 + 1] = v.y;
    tile[r][c0 + j*4 + 2] = v.z; tile[r][c0 + j*4 + 3] = v.w;
  }
  __syncthreads();
  unsigned int pk[8];
#pragma unroll
  for (int j = 0; j < 8; ++j) {
    unsigned int lo = f2bf(tile[c0 + 2*j    ][r]);
    unsigned int hi = f2bf(tile[c0 + 2*j + 1][r]);
    pk[j] = lo | (hi << 16);
  }
  unsigned short* dst = WT + (size_t)(bx + r) * ND + by + c0;
  *reinterpret_cast<uint4*>(dst)     = make_uint4(pk[0], pk[1], pk[2], pk[3]);
  *reinterpret_cast<uint4*>(dst + 8) = make_uint4(pk[4], pk[5], pk[6], pk[7]);
}

// ---------- plain cast f32 -> bf16 (row-major copy) ---------------------------
__global__ __launch_bounds__(256) void cast_w(const float* __restrict__ w,
                                              unsigned short* __restrict__ o) {
  const size_t i4 = ((size_t)blockIdx.x * 256 + threadIdx.x) * 4;
  float4 f = *reinterpret_cast<const float4*>(w + i4);
  ushort4 r;
  r.x = f2bf(f.x); r.y = f2bf(f.y); r.z = f2bf(f.z); r.w = f2bf(f.w);
  *reinterpret_cast<ushort4*>(o + i4) = r;
}

// ---------- tokens + mask + LayerNorm -> F chunk (bf16) -----------------------
__global__ __launch_bounds__(256) void prep_tokens(
    const float* __restrict__ x_start, const int* __restrict__ tarr,
    const float* __restrict__ noise, const float* __restrict__ cond_src,
    const float* __restrict__ cond_tgt, const float* __restrict__ sqrt_ac,
    const float* __restrict__ sqrt_omac, unsigned short* __restrict__ F,
    float* __restrict__ maskf, int b0)
{
  const int cb = blockIdx.y, tok = blockIdx.x, tid = threadIdx.x;
  const int b = b0 + cb;
  const int e0 = tid * 8;
  float v[8];
  if (tok == 0) {
    const int tb = tarr[b];
    const float sa = sqrt_ac[tb], so = sqrt_omac[tb];
    const float4* xs = reinterpret_cast<const float4*>(x_start + (size_t)b * ND + e0);
    const float4* ns = reinterpret_cast<const float4*>(noise + (size_t)b * ND + e0);
    float4 x0 = xs[0], x1 = xs[1], n0 = ns[0], n1 = ns[1];
    v[0] = sa*x0.x + so*n0.x; v[1] = sa*x0.y + so*n0.y;
    v[2] = sa*x0.z + so*n0.z; v[3] = sa*x0.w + so*n0.w;
    v[4] = sa*x1.x + so*n1.x; v[5] = sa*x1.y + so*n1.y;
    v[6] = sa*x1.z + so*n1.z; v[7] = sa*x1.w + so*n1.w;
  } else if (tok == 1) {
    const float tf = (float)tarr[b];
    const float cc = -9.210340371976184f / 1023.0f;  // -ln(10000)/(half-1)
#pragma unroll
    for (int j = 0; j < 8; ++j) {
      int e = e0 + j;
      int i = (e < 1024) ? e : (e - 1024);
      float a = tf * expf((float)i * cc);
      v[j] = (e < 1024) ? sinf(a) : cosf(a);
    }
  } else {
    const float* src = (tok == 2) ? cond_src : cond_tgt;
    const float4* ps = reinterpret_cast<const float4*>(src + (size_t)b * ND + e0);
    float4 a0 = ps[0], a1 = ps[1];
    v[0]=a0.x; v[1]=a0.y; v[2]=a0.z; v[3]=a0.w;
    v[4]=a1.x; v[5]=a1.y; v[6]=a1.z; v[7]=a1.w;
  }
  float s = 0.f, s2 = 0.f, sab = 0.f;
#pragma unroll
  for (int j = 0; j < 8; ++j) { s += v[j]; s2 += v[j]*v[j]; sab += fabsf(v[j]); }
#pragma unroll
  for (int o = 32; o > 0; o >>= 1) {
    s += __shfl_xor(s, o); s2 += __shfl_xor(s2, o); sab += __shfl_xor(sab, o);
  }
  __shared__ float red[12];
  const int lane = tid & 63, wid = tid >> 6;
  if (lane == 0) { red[wid*3+0] = s; red[wid*3+1] = s2; red[wid*3+2] = sab; }
  __syncthreads();
  s   = red[0] + red[3] + red[6] + red[9];
  s2  = red[1] + red[4] + red[7] + red[10];
  sab = red[2] + red[5] + red[8] + red[11];
  const float mu  = s * (1.0f / ND);
  const float var = s2 * (1.0f / ND) - mu * mu;
  const float rs  = rsqrtf(var + 1e-5f);
  if (tid == 0) maskf[(size_t)cb*NT + tok] = (sab > 0.0f) ? 1.0f : 0.0f;
  unsigned int pk[4];
#pragma unroll
  for (int j = 0; j < 4; ++j) {
    unsigned int lo = f2bf((v[2*j]   - mu) * rs);
    unsigned int hi = f2bf((v[2*j+1] - mu) * rs);
    pk[j] = lo | (hi << 16);
  }
  *reinterpret_cast<uint4*>(F + ((size_t)cb*NT + tok) * ND + e0) =
      make_uint4(pk[0], pk[1], pk[2], pk[3]);
}

// ---------- 128^2 GEMM core (swizzled LDS): C=A*B^T, bf16 out -----------------
__global__ __launch_bounds__(256) void gemm_nt_bf16(
    const unsigned short* __restrict__ A, const unsigned short* __restrict__ B,
    unsigned short* __restrict__ C)
{
  constexpr int K = ND;
  __shared__ unsigned short As[128*32];
  __shared__ unsigned short Bs[128*32];
  const int tid = threadIdx.x;
  const int lane = tid & 63, wid = tid >> 6;
  const int wm = wid >> 1, wn = wid & 1;
  const size_t arow0 = (size_t)blockIdx.y * 128;
  const size_t bcol0 = (size_t)blockIdx.x * 128;
  f32x4 acc[4][4] = {};
  const int row0 = tid >> 2, row1 = row0 + 64;
  const int kc = (((tid & 3) ^ ((tid >> 3) & 3))) * 8;   // swizzled source chunk
  const unsigned short* ga0 = A + (arow0 + row0) * K + kc;
  const unsigned short* ga1 = A + (arow0 + row1) * K + kc;
  const unsigned short* gb0 = B + (bcol0 + row0) * K + kc;
  const unsigned short* gb1 = B + (bcol0 + row1) * K + kc;
  char* lAs = (char*)As; char* lBs = (char*)Bs;
  const int lo0 = wid * 1024, lo1 = 4096 + wid * 1024;
  const int ar = (lane & 15);
  const int ko = ((lane >> 4) ^ ((lane >> 1) & 3)) * 8;  // swizzled read chunk
  for (int k0 = 0; k0 < K; k0 += 32) {
    GL2LDS(ga0 + k0, lAs + lo0);
    GL2LDS(ga1 + k0, lAs + lo1);
    GL2LDS(gb0 + k0, lBs + lo0);
    GL2LDS(gb1 + k0, lBs + lo1);
    __syncthreads();
    bf16x8 af[4], bfr[4];
#pragma unroll
    for (int mi = 0; mi < 4; ++mi)
      af[mi] = *reinterpret_cast<const bf16x8*>(&As[(wm*64 + mi*16 + ar)*32 + ko]);
#pragma unroll
    for (int ni = 0; ni < 4; ++ni)
      bfr[ni] = *reinterpret_cast<const bf16x8*>(&Bs[(wn*64 + ni*16 + ar)*32 + ko]);
#pragma unroll
    for (int mi = 0; mi < 4; ++mi)
#pragma unroll
      for (int ni = 0; ni < 4; ++ni)
        acc[mi][ni] = __builtin_amdgcn_mfma_f32_16x16x32_bf16(af[mi], bfr[ni], acc[mi][ni], 0, 0, 0);
    __syncthreads();
  }
#pragma unroll
  for (int mi = 0; mi < 4; ++mi)
#pragma unroll
    for (int ni = 0; ni < 4; ++ni) {
      const size_t col = bcol0 + wn*64 + ni*16 + (lane & 15);
#pragma unroll
      for (int r = 0; r < 4; ++r) {
        const size_t row = arow0 + wm*64 + mi*16 + (lane >> 4)*4 + r;
        C[row * ND + col] = f2bf(acc[mi][ni][r]);
      }
    }
}

// ---------- 256^2 tile, BK=64, ring-2, quadrant-interleaved K-loop ------------
// Per tile: 4 sub-phases {ds_read chunk -> 16 MFMA} pinned by sched_barrier(0)
// so LDS-read and MFMA pipes overlap across the 2 waves/SIMD (no intra-tile
// barriers -> waves drift into read||MFMA stagger). Stages for t+1 (opposite
// ring) issue in sub-phases 1-2 -> >=2 sub-phases before the boundary vmcnt(0).
__global__ __launch_bounds__(512, 2) void gemm_nt_256(
    const unsigned short* __restrict__ A, const unsigned short* __restrict__ B,
    unsigned short* __restrict__ C)
{
  constexpr int K = 2048;
  constexpr int NTILE = K / 64;  // 32
  __shared__ unsigned short lds[65536];  // 128 KiB: 2 rings x (A 32K + B 32K)
  const int tid = threadIdx.x;
  const int lane = tid & 63, wid = tid >> 6;
  const int wm = wid >> 2, wn = wid & 3;

  // XCD-aware swizzle (nwg%8==0 always: nwg = 8*(M/256))
  const int GX = (int)gridDim.x;
  const int nwg = GX * (int)gridDim.y;
  const int o = (int)blockIdx.y * GX + (int)blockIdx.x;
  const int swz = (o & 7) * (nwg >> 3) + (o >> 3);
  const int bx = swz % GX, by = swz / GX;

  const size_t arow0 = (size_t)by * 256;
  const size_t bcol0 = (size_t)bx * 256;
  char* ldsb = (char*)lds;

  // ---- staging: per 32-k half, slot s holds (r=s>>2, c=(s&3)^((r>>1)&3)) ----
  const int s0 = wid*64 + lane, s1 = s0 + 512;
  const int rS0 = s0 >> 2, cS0 = (s0 & 3) ^ ((rS0 >> 1) & 3);
  const int rS1 = s1 >> 2, cS1 = (s1 & 3) ^ ((rS1 >> 1) & 3);
  const unsigned short* gA0 = A + (arow0 + rS0) * K + cS0*8;
  const unsigned short* gA1 = A + (arow0 + rS1) * K + cS1*8;
  const unsigned short* gB0 = B + (bcol0 + rS0) * K + cS0*8;
  const unsigned short* gB1 = B + (bcol0 + rS1) * K + cS1*8;
  const int ldsw0 = wid * 1024;          // slot-group base within a 16K half
  const int ldsw1 = 8192 + wid * 1024;

  // ring q: A k-half h at q*65536 + h*16384; B k-half h at q*65536 + 32768 + h*16384
#define STAGE_AH(tt,h) { const int q_ = ((tt)&1)*65536; const int k_ = (tt)*64 + (h)*32; \
    GL2LDS(gA0 + k_, ldsb + q_ + (h)*16384 + ldsw0);                                     \
    GL2LDS(gA1 + k_, ldsb + q_ + (h)*16384 + ldsw1); }
#define STAGE_BH(tt,h) { const int q_ = ((tt)&1)*65536; const int k_ = (tt)*64 + (h)*32; \
    GL2LDS(gB0 + k_, ldsb + q_ + 32768 + (h)*16384 + ldsw0);                             \
    GL2LDS(gB1 + k_, ldsb + q_ + 32768 + (h)*16384 + ldsw1); }

  // ---- fragment read offset (bytes, within a 16K half region) ----
  const int lo16 = ((lane & 15) * 4 + ((lane >> 4) ^ ((lane >> 1) & 3))) * 16;

  f32x4 acc[8][4] = {};
  bf16x8 aq[4][2], bq[4][2];   // current A-quadrant frags; all B frags

  // prologue: stage tile 0 into ring 0; drain; barrier
  STAGE_AH(0,0); STAGE_AH(0,1); STAGE_BH(0,0); STAGE_BH(0,1);
  waitv0();
  __builtin_amdgcn_s_barrier();

  for (int t = 0; t < NTILE; ++t) {
    const char* rg = ldsb + (t & 1) * 65536;
    // A[mi][kh] @ rg + kh*16384 + wm*8192 + mi*1024 + lo16   (mi 0..7)
    // B[ni][kh] @ rg + 32768 + kh*16384 + wn*4096 + ni*1024 + lo16  (ni 0..3)

    // ---- sub-phase 1 (q00): read A[0..3][*] + B[0..1][*]; stage A(t+1) ----
#pragma unroll
    for (int i = 0; i < 4; ++i)
#pragma unroll
      for (int kh = 0; kh < 2; ++kh)
        aq[i][kh] = *reinterpret_cast<const bf16x8*>(rg + kh*16384 + wm*8192 + i*1024 + lo16);
#pragma unroll
    for (int ni = 0; ni < 2; ++ni)
#pragma unroll
      for (int kh = 0; kh < 2; ++kh)
        bq[ni][kh] = *reinterpret_cast<const bf16x8*>(rg + 32768 + kh*16384 + wn*4096 + ni*1024 + lo16);
    if (t + 1 < NTILE) { STAGE_AH(t+1,0); STAGE_AH(t+1,1); }
    __builtin_amdgcn_sched_barrier(0);
    __builtin_amdgcn_s_setprio(1);
#pragma unroll
    for (int i = 0; i < 4; ++i)
#pragma unroll
      for (int ni = 0; ni < 2; ++ni)
#pragma unroll
        for (int kh = 0; kh < 2; ++kh)
          acc[i][ni] = __builtin_amdgcn_mfma_f32_16x16x32_bf16(aq[i][kh], bq[ni][kh], acc[i][ni], 0, 0, 0);
    __builtin_amdgcn_s_setprio(0);
    __builtin_amdgcn_sched_barrier(0);

    // ---- sub-phase 2 (q01): read B[2..3][*]; stage B(t+1) ----
#pragma unroll
    for (int ni = 2; ni < 4; ++ni)
#pragma unroll
      for (int kh = 0; kh < 2; ++kh)
        bq[ni][kh] = *reinterpret_cast<const bf16x8*>(rg + 32768 + kh*16384 + wn*4096 + ni*1024 + lo16);
    if (t + 1 < NTILE) { STAGE_BH(t+1,0); STAGE_BH(t+1,1); }
    __builtin_amdgcn_sched_barrier(0);
    __builtin_amdgcn_s_setprio(1);
#pragma unroll
    for (int i = 0; i < 4; ++i)
#pragma unroll
      for (int ni = 2; ni < 4; ++ni)
#pragma unroll
        for (int kh = 0; kh < 2; ++kh)
          acc[i][ni] = __builtin_amdgcn_mfma_f32_16x16x32_bf16(aq[i][kh], bq[ni][kh], acc[i][ni], 0, 0, 0);
    __builtin_amdgcn_s_setprio(0);
    __builtin_amdgcn_sched_barrier(0);

    // ---- sub-phase 3 (q11): read A[4..7][*]; MFMA vs B[2..3] ----
#pragma unroll
    for (int i = 0; i < 4; ++i)
#pragma unroll
      for (int kh = 0; kh < 2; ++kh)
        aq[i][kh] = *reinterpret_cast<const bf16x8*>(rg + kh*16384 + wm*8192 + (i+4)*1024 + lo16);
    __builtin_amdgcn_sched_barrier(0);
    __builtin_amdgcn_s_setprio(1);
#pragma unroll
    for (int i = 0; i < 4; ++i)
#pragma unroll
      for (int ni = 2; ni < 4; ++ni)
#pragma unroll
        for (int kh = 0; kh < 2; ++kh)
          acc[i+4][ni] = __builtin_amdgcn_mfma_f32_16x16x32_bf16(aq[i][kh], bq[ni][kh], acc[i+4][ni], 0, 0, 0);
    __builtin_amdgcn_s_setprio(0);
    __builtin_amdgcn_sched_barrier(0);

    // ---- sub-phase 4 (q10): no reads; MFMA vs B[0..1] ----
    __builtin_amdgcn_s_setprio(1);
#pragma unroll
    for (int i = 0; i < 4; ++i)
#pragma unroll
      for (int ni = 0; ni < 2; ++ni)
#pragma unroll
        for (int kh = 0; kh < 2; ++kh)
          acc[i+4][ni] = __builtin_amdgcn_mfma_f32_16x16x32_bf16(aq[i][kh], bq[ni][kh], acc[i+4][ni], 0, 0, 0);
    __builtin_amdgcn_s_setprio(0);

    // ---- boundary: t+1's 8 loads (issued >=2 sub-phases ago) -> sync ----
    waitv0();
    __builtin_amdgcn_s_barrier();
  }
#undef STAGE_AH
#undef STAGE_BH

  // epilogue: C/D layout col=lane&15, row=(lane>>4)*4+reg
#pragma unroll
  for (int mi = 0; mi < 8; ++mi)
#pragma unroll
    for (int ni = 0; ni < 4; ++ni) {
      const size_t col = bcol0 + wn*64 + ni*16 + (lane & 15);
#pragma unroll
      for (int r = 0; r < 4; ++r) {
        const size_t row = arow0 + wm*128 + mi*16 + (lane >> 4)*4 + r;
        C[row * 2048 + col] = f2bf(acc[mi][ni][r]);
      }
    }
}

// ---------- pred GEMM (swizzled LDS): f32 out to d_out(+1) + loss partials ----
__global__ __launch_bounds__(256) void gemm_nt_pred(
    const unsigned short* __restrict__ A, const unsigned short* __restrict__ B,
    float* __restrict__ outp /* = out+1 */, const float* __restrict__ x_start,
    float* __restrict__ lpart, int b0)
{
  constexpr int K = ND;
  __shared__ unsigned short As[128*32];
  __shared__ unsigned short Bs[128*32];
  __shared__ float r2[4];
  const int tid = threadIdx.x;
  const int lane = tid & 63, wid = tid >> 6;
  const int wm = wid >> 1, wn = wid & 1;
  const size_t arow0 = (size_t)blockIdx.y * 128;
  const size_t bcol0 = (size_t)blockIdx.x * 128;
  f32x4 acc[4][4] = {};
  const int row0 = tid >> 2, row1 = row0 + 64;
  const int kc = (((tid & 3) ^ ((tid >> 3) & 3))) * 8;
  const unsigned short* ga0 = A + (arow0 + row0) * K + kc;
  const unsigned short* ga1 = A + (arow0 + row1) * K + kc;
  const unsigned short* gb0 = B + (bcol0 + row0) * K + kc;
  const unsigned short* gb1 = B + (bcol0 + row1) * K + kc;
  char* lAs = (char*)As; char* lBs = (char*)Bs;
  const int lo0 = wid * 1024, lo1 = 4096 + wid * 1024;
  const int ar = (lane & 15);
  const int ko = ((lane >> 4) ^ ((lane >> 1) & 3)) * 8;
  for (int k0 = 0; k0 < K; k0 += 32) {
    GL2LDS(ga0 + k0, lAs + lo0);
    GL2LDS(ga1 + k0, lAs + lo1);
    GL2LDS(gb0 + k0, lBs + lo0);
    GL2LDS(gb1 + k0, lBs + lo1);
    __syncthreads();
    bf16x8 af[4], bfr[4];
#pragma unroll
    for (int mi = 0; mi < 4; ++mi)
      af[mi] = *reinterpret_cast<const bf16x8*>(&As[(wm*64 + mi*16 + ar)*32 + ko]);
#pragma unroll
    for (int ni = 0; ni < 4; ++ni)
      bfr[ni] = *reinterpret_cast<const bf16x8*>(&Bs[(wn*64 + ni*16 + ar)*32 + ko]);
#pragma unroll
    for (int mi = 0; mi < 4; ++mi)
#pragma unroll
      for (int ni = 0; ni < 4; ++ni)
        acc[mi][ni] = __builtin_amdgcn_mfma_f32_16x16x32_bf16(af[mi], bfr[ni], acc[mi][ni], 0, 0, 0);
    __syncthreads();
  }
  float sse = 0.f;
#pragma unroll
  for (int mi = 0; mi < 4; ++mi)
#pragma unroll
    for (int ni = 0; ni < 4; ++ni) {
      const size_t col = bcol0 + wn*64 + ni*16 + (lane & 15);
#pragma unroll
      for (int r = 0; r < 4; ++r) {
        const size_t row = arow0 + wm*64 + mi*16 + (lane >> 4)*4 + r;  // chunk-local b
        const size_t gb  = (size_t)b0 + row;                           // global b
        const float p = acc[mi][ni][r];
        outp[gb * ND + col] = p;
        const float d = p - x_start[gb * ND + col];
        sse += d * d;
      }
    }
#pragma unroll
  for (int o = 32; o > 0; o >>= 1) sse += __shfl_xor(sse, o);
  if (lane == 0) r2[wid] = sse;
  __syncthreads();
  if (tid == 0) {
    const int slot = ((b0 >> 7) + (int)blockIdx.y) * 16 + (int)blockIdx.x;
    lpart[slot] = r2[0] + r2[1] + r2[2] + r2[3];
  }
}

// ---------- per-group: logits from F,H -> softmax -> u = sum_j c_j f_j --------
__global__ __launch_bounds__(256) void attn_u(
    const unsigned short* __restrict__ F, const unsigned short* __restrict__ H,
    const float* __restrict__ maskf, unsigned short* __restrict__ U)
{
  const int cb = blockIdx.x, tid = threadIdx.x;
  const int e0 = tid * 8, lane = tid & 63, wid = tid >> 6;
  __shared__ float red[64];
  float f[4][8], h[4][8];
#pragma unroll
  for (int i = 0; i < 4; ++i) {
    unpack8(*reinterpret_cast<const uint4*>(F + ((size_t)cb*4 + i)*ND + e0), f[i]);
    unpack8(*reinterpret_cast<const uint4*>(H + ((size_t)cb*4 + i)*ND + e0), h[i]);
  }
  float part[16];
#pragma unroll
  for (int i = 0; i < 4; ++i)
#pragma unroll
    for (int j = 0; j < 4; ++j) {
      float p = 0.f;
#pragma unroll
      for (int r = 0; r < 8; ++r) p += f[i][r] * h[j][r];
      part[i*4+j] = p;
    }
#pragma unroll
  for (int idx = 0; idx < 16; ++idx)
#pragma unroll
    for (int o = 32; o > 0; o >>= 1) part[idx] += __shfl_xor(part[idx], o);
  if (lane == 0) {
#pragma unroll
    for (int idx = 0; idx < 16; ++idx) red[wid*16 + idx] = part[idx];
  }
  __syncthreads();
  float lg[16];
#pragma unroll
  for (int idx = 0; idx < 16; ++idx)
    lg[idx] = red[idx] + red[16+idx] + red[32+idx] + red[48+idx];

  const float scale = 0.022097086912079608f;  // 2048^-0.5
  float m[4];
#pragma unroll
  for (int j = 0; j < 4; ++j) m[j] = maskf[(size_t)cb*NT + j];
  const float denom = fmaxf(m[0]+m[1]+m[2]+m[3], 1.0f);
  float c[4] = {0.f, 0.f, 0.f, 0.f};
#pragma unroll
  for (int i = 0; i < 4; ++i) {
    float x[4];
#pragma unroll
    for (int j = 0; j < 4; ++j) x[j] = (m[j] > 0.f) ? lg[i*4+j]*scale : -1e9f;
    const float mx = fmaxf(fmaxf(x[0],x[1]), fmaxf(x[2],x[3]));
    float p[4], sum = 0.f;
#pragma unroll
    for (int j = 0; j < 4; ++j) { p[j] = expf(x[j]-mx); sum += p[j]; }
    const float w = m[i] / (sum * denom);
#pragma unroll
    for (int j = 0; j < 4; ++j) c[j] += p[j] * w;
  }
  unsigned int pk[4];
#pragma unroll
  for (int jj = 0; jj < 4; ++jj) {
    float ulo = c[0]*f[0][2*jj]   + c[1]*f[1][2*jj]   + c[2]*f[2][2*jj]   + c[3]*f[3][2*jj];
    float uhi = c[0]*f[0][2*jj+1] + c[1]*f[1][2*jj+1] + c[2]*f[2][2*jj+1] + c[3]*f[3][2*jj+1];
    pk[jj] = (unsigned int)f2bf(ulo) | ((unsigned int)f2bf(uhi) << 16);
  }
  *reinterpret_cast<uint4*>(U + (size_t)cb*ND + e0) = make_uint4(pk[0],pk[1],pk[2],pk[3]);
}

// ---------- deterministic loss reduce (1024 fixed slots) ----------------------
__global__ __launch_bounds__(256) void loss_final(const float* __restrict__ lpart,
                                                  float* __restrict__ out) {
  const int tid = threadIdx.x;
  float s = 0.f;
  for (int i = tid; i < 1024; i += 256) s += lpart[i];
#pragma unroll
  for (int o = 32; o > 0; o >>= 1) s += __shfl_xor(s, o);
  __shared__ float red[4];
  const int lane = tid & 63, wid = tid >> 6;
  if (lane == 0) red[wid] = s;
  __syncthreads();
  if (tid == 0) out[0] = (red[0]+red[1]+red[2]+red[3]) * (1.0f / 16777216.0f);
}

extern "C" void kernel_launch(void* const* d_in, const int* in_sizes, int n_in,
                              void* d_out, int out_size, void* d_ws, size_t ws_size,
                              hipStream_t stream) {
  const float* x_start   = (const float*)d_in[0];
  const int*   tarr      = (const int*)  d_in[1];
  const float* noise     = (const float*)d_in[2];
  const float* cond_src  = (const float*)d_in[3];
  const float* cond_tgt  = (const float*)d_in[4];
  const float* w_q       = (const float*)d_in[5];
  const float* w_k       = (const float*)d_in[6];
  const float* w_v       = (const float*)d_in[7];
  const float* sqrt_ac   = (const float*)d_in[8];
  const float* sqrt_omac = (const float*)d_in[9];
  float* out = (float*)d_out;
  char*  ws  = (char*)d_ws;

  // adaptive chunk size: need(cb) = 16 MiB (G+Wv) + cb*36880 (F+H+U+mask) + 4 KiB
  size_t CB;
  if      (ws_size >= 318902272ull) CB = 8192;
  else if (ws_size >= 167841792ull) CB = 4096;
  else if (ws_size >=  92311552ull) CB = 2048;
  else if (ws_size >=  54546432ull) CB = 1024;
  else return;  // < 52 MiB workspace: cannot run

  const size_t offG  = 0;
  const size_t offWv = 8388608;
  const size_t offF  = 16777216;
  const size_t szF   = CB * 16384;            // 4*CB*2048*2 bytes
  const size_t offH  = offF + szF;
  const size_t offU  = offH + szF;
  const size_t offMask = offU + CB * 4096;
  const size_t offLp   = offMask + CB * 16;

  unsigned short* G    = (unsigned short*)(ws + offG);
  unsigned short* WvBf = (unsigned short*)(ws + offWv);
  unsigned short* F    = (unsigned short*)(ws + offF);
  unsigned short* H    = (unsigned short*)(ws + offH);
  unsigned short* U    = (unsigned short*)(ws + offU);
  float* maskC = (float*)(ws + offMask);
  float* lpart = (float*)(ws + offLp);
  // setup-phase aliases (dead before chunk 0 writes F/H)
  unsigned short* WqT = F;
  unsigned short* WkT = H;

  transpose_cast<<<dim3(32, 32), 256, 0, stream>>>(w_q, WqT);
  transpose_cast<<<dim3(32, 32), 256, 0, stream>>>(w_k, WkT);
  cast_w<<<dim3(4096), 256, 0, stream>>>(w_v, WvBf);
  gemm_nt_bf16<<<dim3(16, 16), 256, 0, stream>>>(WqT, WkT, G);   // G = Wq^T Wk

  const int nchunks = NB / (int)CB;
  for (int ci = 0; ci < nchunks; ++ci) {
    const int b0 = ci * (int)CB;
    prep_tokens<<<dim3(NT, (int)CB), 256, 0, stream>>>(
        x_start, tarr, noise, cond_src, cond_tgt, sqrt_ac, sqrt_omac, F, maskC, b0);
    gemm_nt_256<<<dim3(ND/256, (NT*(int)CB)/256), 512, 0, stream>>>(F, G, H);  // H = F G^T
    attn_u<<<dim3((int)CB), 256, 0, stream>>>(F, H, maskC, U);
    gemm_nt_pred<<<dim3(16, (int)CB / 128), 256, 0, stream>>>(
        U, WvBf, out + 1, x_start, lpart, b0);                          // pred = U Wv^T
  }
  loss_final<<<dim3(1), 256, 0, stream>>>(lpart, out);
}